// Round 1
// baseline (1033.296 us; speedup 1.0000x reference)
//
#include <hip/hip_runtime.h>
#include <hip/hip_bf16.h>

typedef unsigned short u16;
typedef unsigned int u32;

__device__ __forceinline__ float bf2f(u16 h) {
  return __uint_as_float(((u32)h) << 16);
}
__device__ __forceinline__ float ldconv(const void* p, int i, int fl) {
  return fl ? bf2f(((const u16*)p)[i]) : ((const float*)p)[i];
}

// ---------------------------------------------------------------- dtype sniff
// If the float tensors were quantized to bf16, reading x as u16 gives sane
// magnitudes (<10). If they are fp32, the low halves have mantissa-random
// exponents -> max over 1024 halves is astronomically likely > 1000.
__global__ void k_flag(const void* x, int* flag, float* ssum) {
  __shared__ float red[256];
  int t = threadIdx.x;
  const u16* h = (const u16*)x;
  float m = 0.f;
  for (int i = t; i < 1024; i += 256) {
    float v = fabsf(bf2f(h[i]));
    m = fmaxf(m, v);
  }
  red[t] = m; __syncthreads();
  for (int off = 128; off > 0; off >>= 1) {
    if (t < off) red[t] = fmaxf(red[t], red[t + off]);
    __syncthreads();
  }
  if (t == 0) {
    *flag = (red[0] < 1000.0f) ? 1 : 0;
    *ssum = 0.f;
  }
}

// ------------------------------------------------------- weight conversion
// wbuf layout (floats): W1[0,4096) b1[4096,4160) W2[4160,8256) b2[8256,8320)
// fc1w[8320,24704) fc1b[24704,24960) fc2w[24960,25216) fc2b[25216]
__global__ void k_conv_w(const void* W1, const void* b1, const void* W2, const void* b2,
                         const void* f1w, const void* f1b, const void* f2w, const void* f2b,
                         float* wbuf, const int* flag) {
  int fl = *flag;
  int i = blockIdx.x * blockDim.x + threadIdx.x;
  if (i >= 25217) return;
  float v;
  if (i < 4096)        v = ldconv(W1,  i,        fl);
  else if (i < 4160)   v = ldconv(b1,  i - 4096, fl);
  else if (i < 8256)   v = ldconv(W2,  i - 4160, fl);
  else if (i < 8320)   v = ldconv(b2,  i - 8256, fl);
  else if (i < 24704)  v = ldconv(f1w, i - 8320, fl);
  else if (i < 24960)  v = ldconv(f1b, i - 24704, fl);
  else if (i < 25216)  v = ldconv(f2w, i - 24960, fl);
  else                 v = ldconv(f2b, i - 25216, fl);
  wbuf[i] = v;
}

__global__ void k_conv_x(const void* x, float* xf, int n, const int* flag) {
  int fl = *flag;
  int i = blockIdx.x * blockDim.x + threadIdx.x;
  if (i < n) xf[i] = ldconv(x, i, fl);
}

// ---------------------------------------------------------------- degree/CSR
__global__ void k_deg_init(int* deg, int N) {
  int i = blockIdx.x * blockDim.x + threadIdx.x;
  if (i < N) deg[i] = 1;  // self-loop
}

__global__ void k_deg_count(const int* __restrict__ eidx, int* deg, int E) {
  int e = blockIdx.x * blockDim.x + threadIdx.x;
  if (e < E) atomicAdd(&deg[eidx[E + e]], 1);  // col = target
}

__global__ void k_scan_a(const int* __restrict__ deg, int* csr_ptr, int* bsum, int N) {
  __shared__ int tmp[256];
  int t = threadIdx.x;
  int i = blockIdx.x * 256 + t;
  int c = (i < N) ? (deg[i] - 1) : 0;
  tmp[t] = c; __syncthreads();
  for (int off = 1; off < 256; off <<= 1) {
    int u = (t >= off) ? tmp[t - off] : 0;
    __syncthreads();
    tmp[t] += u;
    __syncthreads();
  }
  if (i < N) csr_ptr[i] = tmp[t] - c;     // exclusive within block
  if (t == 255) bsum[blockIdx.x] = tmp[255];
}

__global__ void k_scan_b(const int* __restrict__ bsum, int* bsum2, int G) {
  __shared__ int tmp[512];
  int t = threadIdx.x;
  int v = (t < G) ? bsum[t] : 0;
  tmp[t] = v; __syncthreads();
  for (int off = 1; off < 512; off <<= 1) {
    int u = (t >= off) ? tmp[t - off] : 0;
    __syncthreads();
    tmp[t] += u;
    __syncthreads();
  }
  if (t < G) bsum2[t] = tmp[t] - v;       // exclusive
}

__global__ void k_scan_c(int* csr_ptr, int* cursor, const int* __restrict__ bsum2,
                         const int* __restrict__ deg, float* dinv, int N) {
  int i = blockIdx.x * 256 + threadIdx.x;
  if (i >= N) return;
  int p = csr_ptr[i] + bsum2[blockIdx.x];
  csr_ptr[i] = p;
  cursor[i] = p;
  dinv[i] = 1.0f / sqrtf((float)deg[i]);
}

__global__ void k_fill(const int* __restrict__ eidx, int* cursor, int* csr_row, int E) {
  int e = blockIdx.x * blockDim.x + threadIdx.x;
  if (e < E) {
    int c = eidx[E + e];
    int pos = atomicAdd(&cursor[c], 1);
    csr_row[pos] = eidx[e];
  }
}

// ------------------------------------------------------------ 64x64 transform
__global__ __launch_bounds__(512) void k_gemm64(const float* __restrict__ in,
                                                const float* __restrict__ Wf,
                                                float* __restrict__ out, int N) {
  __shared__ __align__(16) float Ws[64 * 64];
  __shared__ __align__(16) float xs[8][64];
  int j = threadIdx.x, r = threadIdx.y;
  int tid = r * 64 + j;
  #pragma unroll
  for (int i = tid; i < 4096; i += 512) Ws[i] = Wf[i];
  int row = blockIdx.x * 8 + r;
  xs[r][j] = (row < N) ? in[(size_t)row * 64 + j] : 0.f;
  __syncthreads();
  float acc = 0.f;
  #pragma unroll
  for (int k = 0; k < 64; k++) acc = fmaf(xs[r][k], Ws[k * 64 + j], acc);
  if (row < N) out[(size_t)row * 64 + j] = acc;
}

// --------------------------------------------------- aggregation (CSR gather)
// dst[i,:] = relu( sum_{e in in(i)} dinv[r]*dinv[i]*src[r,:] + dinv[i]^2*src[i,:] + b )
__global__ __launch_bounds__(256) void k_agg(const float* __restrict__ src, float* __restrict__ dst,
                                             const int* __restrict__ csr_row,
                                             const int* __restrict__ csr_ptr,
                                             const int* __restrict__ deg,
                                             const float* __restrict__ dinv,
                                             const float* __restrict__ wbuf, int bias_off, int N) {
  int lane = threadIdx.x & 63;
  int wid = threadIdx.x >> 6;
  int i = blockIdx.x * 4 + wid;
  if (i >= N) return;
  float di = dinv[i];
  int start = csr_ptr[i];
  int cnt = deg[i] - 1;
  float acc = di * di * src[(size_t)i * 64 + lane];
  for (int e = start; e < start + cnt; e++) {
    int r = csr_row[e];
    acc = fmaf(di * dinv[r], src[(size_t)r * 64 + lane], acc);
  }
  float b = wbuf[bias_off + lane];
  dst[(size_t)i * 64 + lane] = fmaxf(acc + b, 0.f);
}

// ------------------------------------------------- fused fc1(relu)+fc2 + ssq
// per node: out = fc2_b + sum_j relu(h . fc1_w[:,j] + fc1_b[j]) * fc2_w[j]
// wave handles 4 nodes; lane owns hidden units 4*lane..4*lane+3.
// fc1_w staged in LDS in two k-chunks of 32 rows (32 KB).
__global__ __launch_bounds__(256) void k_fc(const float* __restrict__ h,
                                            const float* __restrict__ wbuf,
                                            float* __restrict__ outf,
                                            float* __restrict__ ssum, int N) {
  __shared__ __align__(16) float w1s[32 * 256];
  int t = threadIdx.x;
  int lane = t & 63, wid = t >> 6;
  int i0 = (blockIdx.x * 4 + wid) * 4;
  const float* f1 = wbuf + 8320;
  float hv0 = 0.f, hv1 = 0.f, hv2 = 0.f, hv3 = 0.f;
  if (i0 + 0 < N) hv0 = h[(size_t)(i0 + 0) * 64 + lane];
  if (i0 + 1 < N) hv1 = h[(size_t)(i0 + 1) * 64 + lane];
  if (i0 + 2 < N) hv2 = h[(size_t)(i0 + 2) * 64 + lane];
  if (i0 + 3 < N) hv3 = h[(size_t)(i0 + 3) * 64 + lane];
  float acc[4][4] = {{0.f}};
  for (int ph = 0; ph < 2; ph++) {
    __syncthreads();
    for (int i = t; i < 2048; i += 256)
      ((float4*)w1s)[i] = ((const float4*)(f1 + ph * 8192))[i];
    __syncthreads();
    #pragma unroll
    for (int kk = 0; kk < 32; kk++) {
      float4 w4 = *(const float4*)&w1s[kk * 256 + 4 * lane];
      int k = ph * 32 + kk;
      float h0 = __shfl(hv0, k);
      float h1 = __shfl(hv1, k);
      float h2 = __shfl(hv2, k);
      float h3 = __shfl(hv3, k);
      acc[0][0] = fmaf(h0, w4.x, acc[0][0]); acc[0][1] = fmaf(h0, w4.y, acc[0][1]);
      acc[0][2] = fmaf(h0, w4.z, acc[0][2]); acc[0][3] = fmaf(h0, w4.w, acc[0][3]);
      acc[1][0] = fmaf(h1, w4.x, acc[1][0]); acc[1][1] = fmaf(h1, w4.y, acc[1][1]);
      acc[1][2] = fmaf(h1, w4.z, acc[1][2]); acc[1][3] = fmaf(h1, w4.w, acc[1][3]);
      acc[2][0] = fmaf(h2, w4.x, acc[2][0]); acc[2][1] = fmaf(h2, w4.y, acc[2][1]);
      acc[2][2] = fmaf(h2, w4.z, acc[2][2]); acc[2][3] = fmaf(h2, w4.w, acc[2][3]);
      acc[3][0] = fmaf(h3, w4.x, acc[3][0]); acc[3][1] = fmaf(h3, w4.y, acc[3][1]);
      acc[3][2] = fmaf(h3, w4.z, acc[3][2]); acc[3][3] = fmaf(h3, w4.w, acc[3][3]);
    }
  }
  float4 b4 = *(const float4*)(wbuf + 24704 + 4 * lane);
  float4 v4 = *(const float4*)(wbuf + 24960 + 4 * lane);
  float fc2b = wbuf[25216];
  float o[4];
  #pragma unroll
  for (int m = 0; m < 4; m++) {
    float s = fmaxf(acc[m][0] + b4.x, 0.f) * v4.x
            + fmaxf(acc[m][1] + b4.y, 0.f) * v4.y
            + fmaxf(acc[m][2] + b4.z, 0.f) * v4.z
            + fmaxf(acc[m][3] + b4.w, 0.f) * v4.w;
    #pragma unroll
    for (int off = 32; off > 0; off >>= 1) s += __shfl_xor(s, off);
    o[m] = s + fc2b;
  }
  if (lane == 0) {
    float lss = 0.f;
    #pragma unroll
    for (int m = 0; m < 4; m++) {
      if (i0 + m < N) { outf[i0 + m] = o[m]; lss += o[m] * o[m]; }
    }
    atomicAdd(ssum, lss);
  }
}

// ------------------------------------------------------------- L2 norm write
__global__ void k_norm(const float* __restrict__ outf, const float* __restrict__ ssum,
                       void* dout, int N, const int* flag) {
  int i = blockIdx.x * blockDim.x + threadIdx.x;
  if (i >= N) return;
  float denom = fmaxf(sqrtf(*ssum), 1e-12f);
  float v = outf[i] / denom;
  if (*flag) ((__hip_bfloat16*)dout)[i] = __float2bfloat16(v);
  else       ((float*)dout)[i] = v;
}

extern "C" void kernel_launch(void* const* d_in, const int* in_sizes, int n_in,
                              void* d_out, int out_size, void* d_ws, size_t ws_size,
                              hipStream_t stream) {
  const void* x   = d_in[0];
  const int* eidx = (const int*)d_in[1];
  const void* W1  = d_in[2]; const void* b1  = d_in[3];
  const void* W2  = d_in[4]; const void* b2  = d_in[5];
  const void* f1w = d_in[6]; const void* f1b = d_in[7];
  const void* f2w = d_in[8]; const void* f2b = d_in[9];
  int N = in_sizes[0] / 64;
  int E = in_sizes[1] / 2;

  char* ws = (char*)d_ws;
  size_t off = 0;
  auto alloc = [&](size_t b) {
    void* p = ws + off;
    off = (off + b + 255) & ~(size_t)255;
    return p;
  };
  int*   flag  = (int*)  alloc(4);
  float* ssum  = (float*)alloc(4);
  int*   deg   = (int*)  alloc((size_t)N * 4);
  int*   ptr   = (int*)  alloc((size_t)N * 4);
  int*   cur   = (int*)  alloc((size_t)N * 4);
  int*   bsum  = (int*)  alloc(512 * 4);
  int*   bsum2 = (int*)  alloc(512 * 4);
  float* dinv  = (float*)alloc((size_t)N * 4);
  int*   crow  = (int*)  alloc((size_t)E * 4);
  float* wbuf  = (float*)alloc(25217 * 4);
  float* P0    = (float*)alloc((size_t)N * 64 * 4);
  float* P1    = (float*)alloc((size_t)N * 64 * 4);
  float* outf  = (float*)alloc((size_t)N * 4);

  int GN = (N + 255) / 256;
  int GE = (E + 255) / 256;

  k_flag<<<1, 256, 0, stream>>>(x, flag, ssum);
  k_conv_w<<<(25217 + 255) / 256, 256, 0, stream>>>(W1, b1, W2, b2, f1w, f1b, f2w, f2b, wbuf, flag);
  k_conv_x<<<(N * 64 + 255) / 256, 256, 0, stream>>>(x, P0, N * 64, flag);
  k_deg_init<<<GN, 256, 0, stream>>>(deg, N);
  k_deg_count<<<GE, 256, 0, stream>>>(eidx, deg, E);
  k_scan_a<<<GN, 256, 0, stream>>>(deg, ptr, bsum, N);
  k_scan_b<<<1, 512, 0, stream>>>(bsum, bsum2, GN);
  k_scan_c<<<GN, 256, 0, stream>>>(ptr, cur, bsum2, deg, dinv, N);
  k_fill<<<GE, 256, 0, stream>>>(eidx, cur, crow, E);

  // conv1: transform then aggregate (+b1, relu)
  k_gemm64<<<(N + 7) / 8, dim3(64, 8), 0, stream>>>(P0, wbuf + 0, P1, N);
  k_agg<<<(N + 3) / 4, 256, 0, stream>>>(P1, P0, crow, ptr, deg, dinv, wbuf, 4096, N);
  // conv2
  k_gemm64<<<(N + 7) / 8, dim3(64, 8), 0, stream>>>(P0, wbuf + 4160, P1, N);
  k_agg<<<(N + 3) / 4, 256, 0, stream>>>(P1, P0, crow, ptr, deg, dinv, wbuf, 8256, N);
  // fused MLP + sum of squares
  k_fc<<<(N + 15) / 16, 256, 0, stream>>>(P0, wbuf, outf, ssum, N);
  // normalize + write output
  k_norm<<<GN, 256, 0, stream>>>(outf, ssum, d_out, N, flag);
}

// Round 2
// 625.256 us; speedup vs baseline: 1.6526x; 1.6526x over previous
//
#include <hip/hip_runtime.h>
#include <hip/hip_bf16.h>

typedef unsigned short u16;
typedef unsigned int u32;
typedef __attribute__((ext_vector_type(8))) short short8;
typedef __attribute__((ext_vector_type(4))) float f32x4;

__device__ __forceinline__ float bf2f(u16 h) {
  return __uint_as_float(((u32)h) << 16);
}
__device__ __forceinline__ float ldconv(const void* p, int i, int fl) {
  return fl ? bf2f(((const u16*)p)[i]) : ((const float*)p)[i];
}
__device__ __forceinline__ u16 f2bf(float v) {
  __hip_bfloat16 h = __float2bfloat16(v);
  return *(u16*)&h;
}

// ---------------------------------------------------------------- dtype sniff
__global__ void k_flag(const void* x, int* flag, float* ssum) {
  __shared__ float red[256];
  int t = threadIdx.x;
  const u16* h = (const u16*)x;
  float m = 0.f;
  for (int i = t; i < 1024; i += 256) m = fmaxf(m, fabsf(bf2f(h[i])));
  red[t] = m; __syncthreads();
  for (int off = 128; off > 0; off >>= 1) {
    if (t < off) red[t] = fmaxf(red[t], red[t + off]);
    __syncthreads();
  }
  if (t == 0) { *flag = (red[0] < 1000.0f) ? 1 : 0; *ssum = 0.f; }
}

// ------------------------------------------------------- weight conversion
// wbh (u16): W1T [0,4096) W2T [4096,8192) fc1T [8192,24576)   (all [n][k], k=64)
// wbf (f32): b1[0,64) b2[64,128) fc1b[128,384) fc2w[384,640) fc2b[640]
__global__ void k_conv_w(const void* W1, const void* b1, const void* W2, const void* b2,
                         const void* f1w, const void* f1b, const void* f2w, const void* f2b,
                         u16* wbh, float* wbf, const int* flag) {
  int fl = *flag;
  int i = blockIdx.x * blockDim.x + threadIdx.x;
  if (i < 4096) {
    int n = i >> 6, k = i & 63;
    wbh[i] = f2bf(ldconv(W1, k * 64 + n, fl));
  } else if (i < 8192) {
    int j = i - 4096; int n = j >> 6, k = j & 63;
    wbh[i] = f2bf(ldconv(W2, k * 64 + n, fl));
  } else if (i < 24576) {
    int j = i - 8192; int n = j >> 6, k = j & 63;
    wbh[i] = f2bf(ldconv(f1w, k * 256 + n, fl));
  } else if (i < 24576 + 641) {
    int j = i - 24576;
    float v;
    if (j < 64)       v = ldconv(b1,  j,       fl);
    else if (j < 128) v = ldconv(b2,  j - 64,  fl);
    else if (j < 384) v = ldconv(f1b, j - 128, fl);
    else if (j < 640) v = ldconv(f2w, j - 384, fl);
    else              v = ldconv(f2b, 0,       fl);
    wbf[j] = v;
  }
}

// x -> bf16 node features (8 elems/thread)
__global__ void k_conv_x(const void* x, u16* xb, int n8, const int* flag) {
  int fl = *flag;
  int i = blockIdx.x * blockDim.x + threadIdx.x;
  if (i >= n8) return;
  if (fl) {
    ((uint4*)xb)[i] = ((const uint4*)x)[i];
  } else {
    const float* xf = (const float*)x;
    u16 o[8];
    #pragma unroll
    for (int j = 0; j < 8; j++) o[j] = f2bf(xf[i * 8 + j]);
    ((uint4*)xb)[i] = *(uint4*)o;
  }
}

// ---------------------------------------------------------------- degree/CSR
__global__ void k_deg_init(int* deg, int N) {
  int i = blockIdx.x * blockDim.x + threadIdx.x;
  if (i < N) deg[i] = 1;  // self-loop
}

__global__ void k_deg_count(const int* __restrict__ eidx, int* deg, int E) {
  int e = blockIdx.x * blockDim.x + threadIdx.x;
  if (e < E) atomicAdd(&deg[eidx[E + e]], 1);
}

__global__ void k_scan_a(const int* __restrict__ deg, int* csr_ptr, int* bsum, int N) {
  __shared__ int tmp[256];
  int t = threadIdx.x;
  int i = blockIdx.x * 256 + t;
  int c = (i < N) ? (deg[i] - 1) : 0;
  tmp[t] = c; __syncthreads();
  for (int off = 1; off < 256; off <<= 1) {
    int u = (t >= off) ? tmp[t - off] : 0;
    __syncthreads();
    tmp[t] += u;
    __syncthreads();
  }
  if (i < N) csr_ptr[i] = tmp[t] - c;
  if (t == 255) bsum[blockIdx.x] = tmp[255];
}

__global__ void k_scan_b(const int* __restrict__ bsum, int* bsum2, int G) {
  __shared__ int tmp[512];
  int t = threadIdx.x;
  int v = (t < G) ? bsum[t] : 0;
  tmp[t] = v; __syncthreads();
  for (int off = 1; off < 512; off <<= 1) {
    int u = (t >= off) ? tmp[t - off] : 0;
    __syncthreads();
    tmp[t] += u;
    __syncthreads();
  }
  if (t < G) bsum2[t] = tmp[t] - v;
}

__global__ void k_scan_c(int* csr_ptr, int* cursor, const int* __restrict__ bsum2,
                         const int* __restrict__ deg, float* dinv, int N) {
  int i = blockIdx.x * 256 + threadIdx.x;
  if (i >= N) return;
  int p = csr_ptr[i] + bsum2[blockIdx.x];
  csr_ptr[i] = p;
  cursor[i] = p;
  dinv[i] = 1.0f / sqrtf((float)deg[i]);
}

__global__ void k_fill(const int* __restrict__ eidx, int* cursor, int* csr_row, int E) {
  int e = blockIdx.x * blockDim.x + threadIdx.x;
  if (e < E) {
    int c = eidx[E + e];
    int pos = atomicAdd(&cursor[c], 1);
    csr_row[pos] = eidx[e];
  }
}

// ------------------------------------------- transform: out[N,64] = in @ W (MFMA)
// wT is [n][k] packed k=64. LDS stride 72 elems (144B): 2-way bank alias only.
__global__ __launch_bounds__(256) void k_xform(const u16* __restrict__ in,
                                               const u16* __restrict__ wT,
                                               u16* __restrict__ out, int N) {
  __shared__ __align__(16) u16 ws[64 * 72];
  int t = threadIdx.x;
  #pragma unroll
  for (int f = t; f < 512; f += 256) {
    int n = f >> 3, o = f & 7;
    *(float4*)&ws[n * 72 + o * 8] = ((const float4*)wT)[f];
  }
  __syncthreads();
  int lane = t & 63, wid = t >> 6;
  int g = lane >> 4, c = lane & 15;
  int arow = blockIdx.x * 64 + wid * 16 + c;
  short8 a0 = {0, 0, 0, 0, 0, 0, 0, 0}, a1 = {0, 0, 0, 0, 0, 0, 0, 0};
  if (arow < N) {
    a0 = *(const short8*)&in[(size_t)arow * 64 + g * 8];
    a1 = *(const short8*)&in[(size_t)arow * 64 + g * 8 + 32];
  }
  int rbase = blockIdx.x * 64 + wid * 16 + g * 4;
  #pragma unroll
  for (int tile = 0; tile < 4; tile++) {
    short8 b0 = *(const short8*)&ws[(tile * 16 + c) * 72 + g * 8];
    short8 b1 = *(const short8*)&ws[(tile * 16 + c) * 72 + g * 8 + 32];
    f32x4 z = {0.f, 0.f, 0.f, 0.f};
    f32x4 acc = __builtin_amdgcn_mfma_f32_16x16x32_bf16(a0, b0, z, 0, 0, 0);
    acc = __builtin_amdgcn_mfma_f32_16x16x32_bf16(a1, b1, acc, 0, 0, 0);
    #pragma unroll
    for (int r = 0; r < 4; r++) {
      int orow = rbase + r;
      if (orow < N) out[(size_t)orow * 64 + tile * 16 + c] = f2bf(acc[r]);
    }
  }
}

// --------------------------------------------------- aggregation (CSR gather, bf16)
__global__ __launch_bounds__(256) void k_agg(const u16* __restrict__ src, u16* __restrict__ dst,
                                             const int* __restrict__ csr_row,
                                             const int* __restrict__ csr_ptr,
                                             const int* __restrict__ deg,
                                             const float* __restrict__ dinv,
                                             const float* __restrict__ bias, int N) {
  int lane = threadIdx.x & 63;
  int wid = threadIdx.x >> 6;
  int i = blockIdx.x * 4 + wid;
  if (i >= N) return;
  float di = dinv[i];
  int start = csr_ptr[i];
  int cnt = deg[i] - 1;
  float acc = di * di * bf2f(src[(size_t)i * 64 + lane]);
  for (int e = start; e < start + cnt; e++) {
    int r = csr_row[e];
    acc = fmaf(di * dinv[r], bf2f(src[(size_t)r * 64 + lane]), acc);
  }
  dst[(size_t)i * 64 + lane] = f2bf(fmaxf(acc + bias[lane], 0.f));
}

// ----------------------------- fused fc1(relu)+fc2 + ssq via MFMA (wave = 16 nodes)
__global__ __launch_bounds__(256) void k_fc(const u16* __restrict__ h,
                                            const u16* __restrict__ fc1T,
                                            const float* __restrict__ wf,
                                            float* __restrict__ outf,
                                            float* __restrict__ ssum, int N) {
  __shared__ __align__(16) u16 ws[256 * 72];  // 36864 B
  __shared__ float red[16];
  int t = threadIdx.x;
  #pragma unroll
  for (int f = t; f < 2048; f += 256) {
    int n = f >> 3, o = f & 7;
    *(float4*)&ws[n * 72 + o * 8] = ((const float4*)fc1T)[f];
  }
  __syncthreads();
  int lane = t & 63, wid = t >> 6;
  int g = lane >> 4, c = lane & 15;
  int arow = blockIdx.x * 64 + wid * 16 + c;
  short8 a0 = {0, 0, 0, 0, 0, 0, 0, 0}, a1 = {0, 0, 0, 0, 0, 0, 0, 0};
  if (arow < N) {
    a0 = *(const short8*)&h[(size_t)arow * 64 + g * 8];
    a1 = *(const short8*)&h[(size_t)arow * 64 + g * 8 + 32];
  }
  float psum[4] = {0.f, 0.f, 0.f, 0.f};
  #pragma unroll
  for (int tile = 0; tile < 16; tile++) {
    short8 b0 = *(const short8*)&ws[(tile * 16 + c) * 72 + g * 8];
    short8 b1 = *(const short8*)&ws[(tile * 16 + c) * 72 + g * 8 + 32];
    f32x4 z = {0.f, 0.f, 0.f, 0.f};
    f32x4 acc = __builtin_amdgcn_mfma_f32_16x16x32_bf16(a0, b0, z, 0, 0, 0);
    acc = __builtin_amdgcn_mfma_f32_16x16x32_bf16(a1, b1, acc, 0, 0, 0);
    int col = tile * 16 + c;
    float fb = wf[128 + col];
    float fw = wf[384 + col];
    #pragma unroll
    for (int r = 0; r < 4; r++) psum[r] += fmaxf(acc[r] + fb, 0.f) * fw;
  }
  // reduce over the 16 lanes (bits 0-3) holding different cols of same rows
  #pragma unroll
  for (int off = 1; off < 16; off <<= 1) {
    #pragma unroll
    for (int r = 0; r < 4; r++) psum[r] += __shfl_xor(psum[r], off);
  }
  float fc2b = wf[640];
  if (c == 0) {
    float ss = 0.f;
    int rbase = blockIdx.x * 64 + wid * 16 + g * 4;
    #pragma unroll
    for (int r = 0; r < 4; r++) {
      int row = rbase + r;
      if (row < N) {
        float o = psum[r] + fc2b;
        outf[row] = o;
        ss += o * o;
      }
    }
    red[wid * 4 + g] = ss;
  }
  __syncthreads();
  if (t == 0) {
    float s = 0.f;
    #pragma unroll
    for (int j = 0; j < 16; j++) s += red[j];
    atomicAdd(ssum, s);
  }
}

// ------------------------------------------------------------- L2 norm write
__global__ void k_norm(const float* __restrict__ outf, const float* __restrict__ ssum,
                       void* dout, int N, const int* flag) {
  int i = blockIdx.x * blockDim.x + threadIdx.x;
  if (i >= N) return;
  float denom = fmaxf(sqrtf(*ssum), 1e-12f);
  float v = outf[i] / denom;
  if (*flag) ((__hip_bfloat16*)dout)[i] = __float2bfloat16(v);
  else       ((float*)dout)[i] = v;
}

extern "C" void kernel_launch(void* const* d_in, const int* in_sizes, int n_in,
                              void* d_out, int out_size, void* d_ws, size_t ws_size,
                              hipStream_t stream) {
  const void* x   = d_in[0];
  const int* eidx = (const int*)d_in[1];
  const void* W1  = d_in[2]; const void* b1  = d_in[3];
  const void* W2  = d_in[4]; const void* b2  = d_in[5];
  const void* f1w = d_in[6]; const void* f1b = d_in[7];
  const void* f2w = d_in[8]; const void* f2b = d_in[9];
  int N = in_sizes[0] / 64;
  int E = in_sizes[1] / 2;

  char* ws = (char*)d_ws;
  size_t off = 0;
  auto alloc = [&](size_t b) {
    void* p = ws + off;
    off = (off + b + 255) & ~(size_t)255;
    return p;
  };
  int*   flag  = (int*)  alloc(4);
  float* ssum  = (float*)alloc(4);
  int*   deg   = (int*)  alloc((size_t)N * 4);
  int*   ptr   = (int*)  alloc((size_t)N * 4);
  int*   cur   = (int*)  alloc((size_t)N * 4);
  int*   bsum  = (int*)  alloc(512 * 4);
  int*   bsum2 = (int*)  alloc(512 * 4);
  float* dinv  = (float*)alloc((size_t)N * 4);
  int*   crow  = (int*)  alloc((size_t)E * 4);
  u16*   wbh   = (u16*)  alloc(24576 * 2);
  float* wbf   = (float*)alloc(641 * 4);
  u16*   HA    = (u16*)  alloc((size_t)N * 64 * 2);
  u16*   HT    = (u16*)  alloc((size_t)N * 64 * 2);
  float* outf  = (float*)alloc((size_t)N * 4);

  int GN = (N + 255) / 256;
  int GE = (E + 255) / 256;
  int NT = (N + 63) / 64;

  k_flag<<<1, 256, 0, stream>>>(x, flag, ssum);
  k_conv_w<<<(24576 + 641 + 255) / 256, 256, 0, stream>>>(W1, b1, W2, b2, f1w, f1b, f2w, f2b,
                                                          wbh, wbf, flag);
  k_conv_x<<<(N * 64 / 8 + 255) / 256, 256, 0, stream>>>(x, HA, N * 64 / 8, flag);
  k_deg_init<<<GN, 256, 0, stream>>>(deg, N);
  k_deg_count<<<GE, 256, 0, stream>>>(eidx, deg, E);
  k_scan_a<<<GN, 256, 0, stream>>>(deg, ptr, bsum, N);
  k_scan_b<<<1, 512, 0, stream>>>(bsum, bsum2, GN);
  k_scan_c<<<GN, 256, 0, stream>>>(ptr, cur, bsum2, deg, dinv, N);
  k_fill<<<GE, 256, 0, stream>>>(eidx, cur, crow, E);

  // conv1
  k_xform<<<NT, 256, 0, stream>>>(HA, wbh + 0, HT, N);
  k_agg<<<(N + 3) / 4, 256, 0, stream>>>(HT, HA, crow, ptr, deg, dinv, wbf + 0, N);
  // conv2
  k_xform<<<NT, 256, 0, stream>>>(HA, wbh + 4096, HT, N);
  k_agg<<<(N + 3) / 4, 256, 0, stream>>>(HT, HA, crow, ptr, deg, dinv, wbf + 64, N);
  // fused MLP + sum of squares
  k_fc<<<NT, 256, 0, stream>>>(HA, wbh + 8192, wbf, outf, ssum, N);
  // normalize + write
  k_norm<<<GN, 256, 0, stream>>>(outf, ssum, d_out, N, flag);
}

// Round 3
// 455.528 us; speedup vs baseline: 2.2683x; 1.3726x over previous
//
#include <hip/hip_runtime.h>
#include <hip/hip_bf16.h>

typedef unsigned short u16;
typedef unsigned int u32;
typedef __attribute__((ext_vector_type(8))) short short8;
typedef __attribute__((ext_vector_type(4))) float f32x4;

__device__ __forceinline__ float bf2f(u16 h) {
  return __uint_as_float(((u32)h) << 16);
}
__device__ __forceinline__ float ldconv(const void* p, int i, int fl) {
  return fl ? bf2f(((const u16*)p)[i]) : ((const float*)p)[i];
}
__device__ __forceinline__ u16 f2bf(float v) {
  __hip_bfloat16 h = __float2bfloat16(v);
  return *(u16*)&h;
}

// ---------------------------------------------------------------- dtype sniff
__global__ void k_flag(const void* x, int* flag, float* ssum) {
  __shared__ float red[256];
  int t = threadIdx.x;
  const u16* h = (const u16*)x;
  float m = 0.f;
  for (int i = t; i < 1024; i += 256) m = fmaxf(m, fabsf(bf2f(h[i])));
  red[t] = m; __syncthreads();
  for (int off = 128; off > 0; off >>= 1) {
    if (t < off) red[t] = fmaxf(red[t], red[t + off]);
    __syncthreads();
  }
  if (t == 0) { *flag = (red[0] < 1000.0f) ? 1 : 0; *ssum = 0.f; }
}

// ------------------------------------------------------- weight conversion
// wbh (u16): W1T [0,4096) W2T [4096,8192) fc1T [8192,24576)   (all [n][k], k=64)
// wbf (f32): b1[0,64) b2[64,128) fc1b[128,384) fc2w[384,640) fc2b[640]
__global__ void k_conv_w(const void* W1, const void* b1, const void* W2, const void* b2,
                         const void* f1w, const void* f1b, const void* f2w, const void* f2b,
                         u16* wbh, float* wbf, const int* flag) {
  int fl = *flag;
  int i = blockIdx.x * blockDim.x + threadIdx.x;
  if (i < 4096) {
    int n = i >> 6, k = i & 63;
    wbh[i] = f2bf(ldconv(W1, k * 64 + n, fl));
  } else if (i < 8192) {
    int j = i - 4096; int n = j >> 6, k = j & 63;
    wbh[i] = f2bf(ldconv(W2, k * 64 + n, fl));
  } else if (i < 24576) {
    int j = i - 8192; int n = j >> 6, k = j & 63;
    wbh[i] = f2bf(ldconv(f1w, k * 256 + n, fl));
  } else if (i < 24576 + 641) {
    int j = i - 24576;
    float v;
    if (j < 64)       v = ldconv(b1,  j,       fl);
    else if (j < 128) v = ldconv(b2,  j - 64,  fl);
    else if (j < 384) v = ldconv(f1b, j - 128, fl);
    else if (j < 640) v = ldconv(f2w, j - 384, fl);
    else              v = ldconv(f2b, 0,       fl);
    wbf[j] = v;
  }
}

// x -> bf16 node features (8 elems/thread)
__global__ void k_conv_x(const void* x, u16* xb, int n8, const int* flag) {
  int fl = *flag;
  int i = blockIdx.x * blockDim.x + threadIdx.x;
  if (i >= n8) return;
  if (fl) {
    ((uint4*)xb)[i] = ((const uint4*)x)[i];
  } else {
    const float* xf = (const float*)x;
    u16 o[8];
    #pragma unroll
    for (int j = 0; j < 8; j++) o[j] = f2bf(xf[i * 8 + j]);
    ((uint4*)xb)[i] = *(uint4*)o;
  }
}

// ---------------------------------------------------------------- degree/CSR
__global__ void k_deg_init(int* deg, int N) {
  int i = blockIdx.x * blockDim.x + threadIdx.x;
  if (i < N) deg[i] = 1;  // self-loop
}

__global__ void k_deg_count(const int* __restrict__ eidx, int* deg, int E) {
  int e = blockIdx.x * blockDim.x + threadIdx.x;
  if (e < E) atomicAdd(&deg[eidx[E + e]], 1);
}

__global__ void k_scan_a(const int* __restrict__ deg, int* csr_ptr, int* bsum, int N) {
  __shared__ int tmp[256];
  int t = threadIdx.x;
  int i = blockIdx.x * 256 + t;
  int c = (i < N) ? (deg[i] - 1) : 0;
  tmp[t] = c; __syncthreads();
  for (int off = 1; off < 256; off <<= 1) {
    int u = (t >= off) ? tmp[t - off] : 0;
    __syncthreads();
    tmp[t] += u;
    __syncthreads();
  }
  if (i < N) csr_ptr[i] = tmp[t] - c;
  if (t == 255) bsum[blockIdx.x] = tmp[255];
}

__global__ void k_scan_b(const int* __restrict__ bsum, int* bsum2, int G) {
  __shared__ int tmp[512];
  int t = threadIdx.x;
  int v = (t < G) ? bsum[t] : 0;
  tmp[t] = v; __syncthreads();
  for (int off = 1; off < 512; off <<= 1) {
    int u = (t >= off) ? tmp[t - off] : 0;
    __syncthreads();
    tmp[t] += u;
    __syncthreads();
  }
  if (t < G) bsum2[t] = tmp[t] - v;
}

__global__ void k_scan_c(int* csr_ptr, int* cursor, const int* __restrict__ bsum2,
                         const int* __restrict__ deg, float* dinv, int N) {
  int i = blockIdx.x * 256 + threadIdx.x;
  if (i >= N) return;
  int p = csr_ptr[i] + bsum2[blockIdx.x];
  csr_ptr[i] = p;
  cursor[i] = p;
  dinv[i] = 1.0f / sqrtf((float)deg[i]);
}

__global__ void k_fill(const int* __restrict__ eidx, int* cursor, int* csr_row, int E) {
  int e = blockIdx.x * blockDim.x + threadIdx.x;
  if (e < E) {
    int c = eidx[E + e];
    int pos = atomicAdd(&cursor[c], 1);
    csr_row[pos] = eidx[e];
  }
}

// ---------------- transform: out[r,:] = dinv[r] * (in[r,:] @ W)  (MFMA, bf16)
// wT is [n][k] packed k=64. LDS stride 72 elems (144B): 2-way bank alias only.
__global__ __launch_bounds__(256) void k_xform(const u16* __restrict__ in,
                                               const u16* __restrict__ wT,
                                               const float* __restrict__ dinv,
                                               u16* __restrict__ out, int N) {
  __shared__ __align__(16) u16 ws[64 * 72];
  int t = threadIdx.x;
  #pragma unroll
  for (int f = t; f < 512; f += 256) {
    int n = f >> 3, o = f & 7;
    *(float4*)&ws[n * 72 + o * 8] = ((const float4*)wT)[f];
  }
  __syncthreads();
  int lane = t & 63, wid = t >> 6;
  int g = lane >> 4, c = lane & 15;
  int arow = blockIdx.x * 64 + wid * 16 + c;
  short8 a0 = {0, 0, 0, 0, 0, 0, 0, 0}, a1 = {0, 0, 0, 0, 0, 0, 0, 0};
  if (arow < N) {
    a0 = *(const short8*)&in[(size_t)arow * 64 + g * 8];
    a1 = *(const short8*)&in[(size_t)arow * 64 + g * 8 + 32];
  }
  int rbase = blockIdx.x * 64 + wid * 16 + g * 4;
  float dv[4];
  #pragma unroll
  for (int r = 0; r < 4; r++) dv[r] = (rbase + r < N) ? dinv[rbase + r] : 0.f;
  #pragma unroll
  for (int tile = 0; tile < 4; tile++) {
    short8 b0 = *(const short8*)&ws[(tile * 16 + c) * 72 + g * 8];
    short8 b1 = *(const short8*)&ws[(tile * 16 + c) * 72 + g * 8 + 32];
    f32x4 z = {0.f, 0.f, 0.f, 0.f};
    f32x4 acc = __builtin_amdgcn_mfma_f32_16x16x32_bf16(a0, b0, z, 0, 0, 0);
    acc = __builtin_amdgcn_mfma_f32_16x16x32_bf16(a1, b1, acc, 0, 0, 0);
    #pragma unroll
    for (int r = 0; r < 4; r++) {
      int orow = rbase + r;
      if (orow < N) out[(size_t)orow * 64 + tile * 16 + c] = f2bf(acc[r] * dv[r]);
    }
  }
}

// ---------------- aggregation: dst[i,:] = relu(dinv[i]*(sum of pre-scaled rows) + b)
// wave = 1 node; 4 subgroups of 16 lanes; lane owns 4 features (uint2 = 4 bf16).
// Each wave-wide load instruction covers 4 edges (512 B) -> 4-8 gathers in flight.
__global__ __launch_bounds__(256) void k_agg(const u16* __restrict__ src, u16* __restrict__ dst,
                                             const int* __restrict__ csr_row,
                                             const int* __restrict__ csr_ptr,
                                             const int* __restrict__ deg,
                                             const float* __restrict__ dinv,
                                             const float* __restrict__ bias, int N) {
  int lane = threadIdx.x & 63;
  int wid = threadIdx.x >> 6;
  int i = blockIdx.x * 4 + wid;
  if (i >= N) return;
  int sub = lane >> 4;
  int fq  = lane & 15;                 // features 4*fq .. 4*fq+3
  int start = csr_ptr[i];
  int total = deg[i];                  // (deg-1) real edges + 1 self (virtual t=0)
  const u16* base = src + (size_t)fq * 4;
  float a0 = 0.f, a1 = 0.f, a2 = 0.f, a3 = 0.f;
  #pragma unroll 2
  for (int t = sub; t < total; t += 4) {
    int r = (t == 0) ? i : csr_row[start + t - 1];
    uint2 v = *(const uint2*)(base + (size_t)r * 64);
    a0 += __uint_as_float(v.x << 16);
    a1 += __uint_as_float(v.x & 0xffff0000u);
    a2 += __uint_as_float(v.y << 16);
    a3 += __uint_as_float(v.y & 0xffff0000u);
  }
  a0 += __shfl_xor(a0, 16); a1 += __shfl_xor(a1, 16);
  a2 += __shfl_xor(a2, 16); a3 += __shfl_xor(a3, 16);
  a0 += __shfl_xor(a0, 32); a1 += __shfl_xor(a1, 32);
  a2 += __shfl_xor(a2, 32); a3 += __shfl_xor(a3, 32);
  if (sub == 0) {
    float di = dinv[i];
    float4 b4 = ((const float4*)bias)[fq];
    u16 o[4];
    o[0] = f2bf(fmaxf(fmaf(a0, di, b4.x), 0.f));
    o[1] = f2bf(fmaxf(fmaf(a1, di, b4.y), 0.f));
    o[2] = f2bf(fmaxf(fmaf(a2, di, b4.z), 0.f));
    o[3] = f2bf(fmaxf(fmaf(a3, di, b4.w), 0.f));
    *(uint2*)&dst[(size_t)i * 64 + fq * 4] = *(uint2*)o;
  }
}

// ----------------------------- fused fc1(relu)+fc2 + ssq via MFMA (wave = 16 nodes)
__global__ __launch_bounds__(256) void k_fc(const u16* __restrict__ h,
                                            const u16* __restrict__ fc1T,
                                            const float* __restrict__ wf,
                                            float* __restrict__ outf,
                                            float* __restrict__ ssum, int N) {
  __shared__ __align__(16) u16 ws[256 * 72];  // 36864 B
  __shared__ float red[16];
  int t = threadIdx.x;
  #pragma unroll
  for (int f = t; f < 2048; f += 256) {
    int n = f >> 3, o = f & 7;
    *(float4*)&ws[n * 72 + o * 8] = ((const float4*)fc1T)[f];
  }
  __syncthreads();
  int lane = t & 63, wid = t >> 6;
  int g = lane >> 4, c = lane & 15;
  int arow = blockIdx.x * 64 + wid * 16 + c;
  short8 a0 = {0, 0, 0, 0, 0, 0, 0, 0}, a1 = {0, 0, 0, 0, 0, 0, 0, 0};
  if (arow < N) {
    a0 = *(const short8*)&h[(size_t)arow * 64 + g * 8];
    a1 = *(const short8*)&h[(size_t)arow * 64 + g * 8 + 32];
  }
  float psum[4] = {0.f, 0.f, 0.f, 0.f};
  #pragma unroll
  for (int tile = 0; tile < 16; tile++) {
    short8 b0 = *(const short8*)&ws[(tile * 16 + c) * 72 + g * 8];
    short8 b1 = *(const short8*)&ws[(tile * 16 + c) * 72 + g * 8 + 32];
    f32x4 z = {0.f, 0.f, 0.f, 0.f};
    f32x4 acc = __builtin_amdgcn_mfma_f32_16x16x32_bf16(a0, b0, z, 0, 0, 0);
    acc = __builtin_amdgcn_mfma_f32_16x16x32_bf16(a1, b1, acc, 0, 0, 0);
    int col = tile * 16 + c;
    float fb = wf[128 + col];
    float fw = wf[384 + col];
    #pragma unroll
    for (int r = 0; r < 4; r++) psum[r] += fmaxf(acc[r] + fb, 0.f) * fw;
  }
  #pragma unroll
  for (int off = 1; off < 16; off <<= 1) {
    #pragma unroll
    for (int r = 0; r < 4; r++) psum[r] += __shfl_xor(psum[r], off);
  }
  float fc2b = wf[640];
  if (c == 0) {
    float ss = 0.f;
    int rbase = blockIdx.x * 64 + wid * 16 + g * 4;
    #pragma unroll
    for (int r = 0; r < 4; r++) {
      int row = rbase + r;
      if (row < N) {
        float o = psum[r] + fc2b;
        outf[row] = o;
        ss += o * o;
      }
    }
    red[wid * 4 + g] = ss;
  }
  __syncthreads();
  if (t == 0) {
    float s = 0.f;
    #pragma unroll
    for (int j = 0; j < 16; j++) s += red[j];
    atomicAdd(ssum, s);
  }
}

// ------------------------------------------------------------- L2 norm write
__global__ void k_norm(const float* __restrict__ outf, const float* __restrict__ ssum,
                       void* dout, int N, const int* flag) {
  int i = blockIdx.x * blockDim.x + threadIdx.x;
  if (i >= N) return;
  float denom = fmaxf(sqrtf(*ssum), 1e-12f);
  float v = outf[i] / denom;
  if (*flag) ((__hip_bfloat16*)dout)[i] = __float2bfloat16(v);
  else       ((float*)dout)[i] = v;
}

extern "C" void kernel_launch(void* const* d_in, const int* in_sizes, int n_in,
                              void* d_out, int out_size, void* d_ws, size_t ws_size,
                              hipStream_t stream) {
  const void* x   = d_in[0];
  const int* eidx = (const int*)d_in[1];
  const void* W1  = d_in[2]; const void* b1  = d_in[3];
  const void* W2  = d_in[4]; const void* b2  = d_in[5];
  const void* f1w = d_in[6]; const void* f1b = d_in[7];
  const void* f2w = d_in[8]; const void* f2b = d_in[9];
  int N = in_sizes[0] / 64;
  int E = in_sizes[1] / 2;

  char* ws = (char*)d_ws;
  size_t off = 0;
  auto alloc = [&](size_t b) {
    void* p = ws + off;
    off = (off + b + 255) & ~(size_t)255;
    return p;
  };
  int*   flag  = (int*)  alloc(4);
  float* ssum  = (float*)alloc(4);
  int*   deg   = (int*)  alloc((size_t)N * 4);
  int*   ptr   = (int*)  alloc((size_t)N * 4);
  int*   cur   = (int*)  alloc((size_t)N * 4);
  int*   bsum  = (int*)  alloc(512 * 4);
  int*   bsum2 = (int*)  alloc(512 * 4);
  float* dinv  = (float*)alloc((size_t)N * 4);
  int*   crow  = (int*)  alloc((size_t)E * 4);
  u16*   wbh   = (u16*)  alloc(24576 * 2);
  float* wbf   = (float*)alloc(641 * 4);
  u16*   HA    = (u16*)  alloc((size_t)N * 64 * 2);
  u16*   HT    = (u16*)  alloc((size_t)N * 64 * 2);
  float* outf  = (float*)alloc((size_t)N * 4);

  int GN = (N + 255) / 256;
  int GE = (E + 255) / 256;
  int NT = (N + 63) / 64;

  k_flag<<<1, 256, 0, stream>>>(x, flag, ssum);
  k_conv_w<<<(24576 + 641 + 255) / 256, 256, 0, stream>>>(W1, b1, W2, b2, f1w, f1b, f2w, f2b,
                                                          wbh, wbf, flag);
  k_conv_x<<<(N * 64 / 8 + 255) / 256, 256, 0, stream>>>(x, HA, N * 64 / 8, flag);
  k_deg_init<<<GN, 256, 0, stream>>>(deg, N);
  k_deg_count<<<GE, 256, 0, stream>>>(eidx, deg, E);
  k_scan_a<<<GN, 256, 0, stream>>>(deg, ptr, bsum, N);
  k_scan_b<<<1, 512, 0, stream>>>(bsum, bsum2, GN);
  k_scan_c<<<GN, 256, 0, stream>>>(ptr, cur, bsum2, deg, dinv, N);
  k_fill<<<GE, 256, 0, stream>>>(eidx, cur, crow, E);

  // conv1
  k_xform<<<NT, 256, 0, stream>>>(HA, wbh + 0, dinv, HT, N);
  k_agg<<<(N + 3) / 4, 256, 0, stream>>>(HT, HA, crow, ptr, deg, dinv, wbf + 0, N);
  // conv2
  k_xform<<<NT, 256, 0, stream>>>(HA, wbh + 4096, dinv, HT, N);
  k_agg<<<(N + 3) / 4, 256, 0, stream>>>(HT, HA, crow, ptr, deg, dinv, wbf + 64, N);
  // fused MLP + sum of squares
  k_fc<<<NT, 256, 0, stream>>>(HA, wbh + 8192, wbf, outf, ssum, N);
  // normalize + write
  k_norm<<<GN, 256, 0, stream>>>(outf, ssum, d_out, N, flag);
}

// Round 4
// 318.354 us; speedup vs baseline: 3.2457x; 1.4309x over previous
//
#include <hip/hip_runtime.h>
#include <hip/hip_bf16.h>

typedef unsigned short u16;
typedef unsigned int u32;
typedef __attribute__((ext_vector_type(8))) short short8;
typedef __attribute__((ext_vector_type(4))) float f32x4;

__device__ __forceinline__ float bf2f(u16 h) {
  return __uint_as_float(((u32)h) << 16);
}
__device__ __forceinline__ float ldconv(const void* p, int i, int fl) {
  return fl ? bf2f(((const u16*)p)[i]) : ((const float*)p)[i];
}
__device__ __forceinline__ u16 f2bf(float v) {
  __hip_bfloat16 h = __float2bfloat16(v);
  return *(u16*)&h;
}

// ---------------------------------------------------------------- dtype sniff
__global__ void k_flag(const void* x, int* flag, float* ssum, int* bcnt) {
  __shared__ float red[256];
  int t = threadIdx.x;
  const u16* h = (const u16*)x;
  float m = 0.f;
  for (int i = t; i < 1024; i += 256) m = fmaxf(m, fabsf(bf2f(h[i])));
  red[t] = m; __syncthreads();
  for (int off = 128; off > 0; off >>= 1) {
    if (t < off) red[t] = fmaxf(red[t], red[t + off]);
    __syncthreads();
  }
  bcnt[t] = 0;
  if (t == 0) { *flag = (red[0] < 1000.0f) ? 1 : 0; *ssum = 0.f; }
}

// ------------------------------------------------------- weight conversion
// wbh (u16): W1T [0,4096) W2T [4096,8192) fc1T [8192,24576)   (all [n][k], k=64)
// wbf (f32): b1[0,64) b2[64,128) fc1b[128,384) fc2w[384,640) fc2b[640]
__global__ void k_conv_w(const void* W1, const void* b1, const void* W2, const void* b2,
                         const void* f1w, const void* f1b, const void* f2w, const void* f2b,
                         u16* wbh, float* wbf, const int* flag) {
  int fl = *flag;
  int i = blockIdx.x * blockDim.x + threadIdx.x;
  if (i < 4096) {
    int n = i >> 6, k = i & 63;
    wbh[i] = f2bf(ldconv(W1, k * 64 + n, fl));
  } else if (i < 8192) {
    int j = i - 4096; int n = j >> 6, k = j & 63;
    wbh[i] = f2bf(ldconv(W2, k * 64 + n, fl));
  } else if (i < 24576) {
    int j = i - 8192; int n = j >> 6, k = j & 63;
    wbh[i] = f2bf(ldconv(f1w, k * 256 + n, fl));
  } else if (i < 24576 + 641) {
    int j = i - 24576;
    float v;
    if (j < 64)       v = ldconv(b1,  j,       fl);
    else if (j < 128) v = ldconv(b2,  j - 64,  fl);
    else if (j < 384) v = ldconv(f1b, j - 128, fl);
    else if (j < 640) v = ldconv(f2w, j - 384, fl);
    else              v = ldconv(f2b, 0,       fl);
    wbf[j] = v;
  }
}

// --------------------------------------- bucketed CSR build (256 buckets)
// Pass A: per-block LDS histogram -> 256 global atomics per block.
__global__ __launch_bounds__(256) void k_bcount(const int* __restrict__ eidx, int E, int npb,
                                                int* bcnt) {
  __shared__ int hist[256];
  int t = threadIdx.x;
  hist[t] = 0;
  __syncthreads();
  int e0 = blockIdx.x * 8192;
  int e1 = min(e0 + 8192, E);
  for (int e = e0 + t; e < e1; e += 256) {
    int tgt = eidx[E + e];
    atomicAdd(&hist[tgt / npb], 1);
  }
  __syncthreads();
  if (hist[t]) atomicAdd(&bcnt[t], hist[t]);
}

// exclusive scan of 256 bucket counts -> bbase (persist) and bcur (running)
__global__ void k_bscan(const int* __restrict__ bcnt, int* bbase, int* bcur) {
  __shared__ int tmp[256];
  int t = threadIdx.x;
  int v = bcnt[t];
  tmp[t] = v; __syncthreads();
  for (int off = 1; off < 256; off <<= 1) {
    int u = (t >= off) ? tmp[t - off] : 0;
    __syncthreads();
    tmp[t] += u;
    __syncthreads();
  }
  bbase[t] = tmp[t] - v;
  bcur[t]  = tmp[t] - v;
}

// Pass B: reserve per-(block,bucket) runs, scatter packed (src<<9)|tgt_local.
__global__ __launch_bounds__(256) void k_bfill(const int* __restrict__ eidx, int E, int npb,
                                               int* bcur, u32* bdata) {
  __shared__ int hist[256];
  __shared__ int base[256];
  int t = threadIdx.x;
  hist[t] = 0;
  __syncthreads();
  int e0 = blockIdx.x * 8192;
  int e1 = min(e0 + 8192, E);
  for (int e = e0 + t; e < e1; e += 256) {
    int tgt = eidx[E + e];
    atomicAdd(&hist[tgt / npb], 1);
  }
  __syncthreads();
  base[t] = hist[t] ? atomicAdd(&bcur[t], hist[t]) : 0;
  hist[t] = 0;
  __syncthreads();
  for (int e = e0 + t; e < e1; e += 256) {
    int src = eidx[e];
    int tgt = eidx[E + e];
    int b = tgt / npb;
    int idx = atomicAdd(&hist[b], 1);
    bdata[base[b] + idx] = ((u32)src << 9) | (u32)(tgt - b * npb);
  }
}

// degrees from bucket data (LDS histogram, no global atomics); +1 self-loop
__global__ __launch_bounds__(256) void k_degb(const u32* __restrict__ bdata,
                                              const int* __restrict__ bbase,
                                              const int* __restrict__ bcnt,
                                              int* deg, int N, int npb) {
  __shared__ int hist[512];
  int b = blockIdx.x, t = threadIdx.x;
  int node0 = b * npb;
  if (node0 >= N) return;
  int ncnt = min(npb, N - node0);
  for (int j = t; j < 512; j += 256) hist[j] = 0;
  __syncthreads();
  int base = bbase[b], cnt = bcnt[b];
  for (int e = t; e < cnt; e += 256) atomicAdd(&hist[bdata[base + e] & 511], 1);
  __syncthreads();
  for (int j = t; j < ncnt; j += 256) deg[node0 + j] = hist[j] + 1;
}

__global__ void k_scan_a(const int* __restrict__ deg, int* csr_ptr, int* bsum, int N) {
  __shared__ int tmp[256];
  int t = threadIdx.x;
  int i = blockIdx.x * 256 + t;
  int c = (i < N) ? (deg[i] - 1) : 0;
  tmp[t] = c; __syncthreads();
  for (int off = 1; off < 256; off <<= 1) {
    int u = (t >= off) ? tmp[t - off] : 0;
    __syncthreads();
    tmp[t] += u;
    __syncthreads();
  }
  if (i < N) csr_ptr[i] = tmp[t] - c;
  if (t == 255) bsum[blockIdx.x] = tmp[255];
}

__global__ void k_scan_b(const int* __restrict__ bsum, int* bsum2, int G) {
  __shared__ int tmp[512];
  int t = threadIdx.x;
  int v = (t < G) ? bsum[t] : 0;
  tmp[t] = v; __syncthreads();
  for (int off = 1; off < 512; off <<= 1) {
    int u = (t >= off) ? tmp[t - off] : 0;
    __syncthreads();
    tmp[t] += u;
    __syncthreads();
  }
  if (t < G) bsum2[t] = tmp[t] - v;
}

__global__ void k_scan_c(int* csr_ptr, const int* __restrict__ bsum2,
                         const int* __restrict__ deg, float* dinv, int N) {
  int i = blockIdx.x * 256 + threadIdx.x;
  if (i >= N) return;
  csr_ptr[i] += bsum2[blockIdx.x];
  dinv[i] = 1.0f / sqrtf((float)deg[i]);
}

// Pass 2: fine scatter into CSR order inside LDS, then one sequential write.
__global__ __launch_bounds__(256) void k_p2(const u32* __restrict__ bdata,
                                            const int* __restrict__ bbase,
                                            const int* __restrict__ bcnt,
                                            const int* __restrict__ csr_ptr,
                                            int* __restrict__ crow, int N, int npb, int E) {
  __shared__ int lds[8192];
  __shared__ int cur[512];
  int b = blockIdx.x, t = threadIdx.x;
  int node0 = b * npb;
  if (node0 >= N) return;
  int ncnt = min(npb, N - node0);
  int rs = csr_ptr[node0];
  int re = (node0 + ncnt < N) ? csr_ptr[node0 + ncnt] : E;
  for (int j = t; j < ncnt; j += 256) cur[j] = csr_ptr[node0 + j] - rs;
  __syncthreads();
  int base = bbase[b], cnt = bcnt[b];
  for (int e = t; e < cnt; e += 256) {
    u32 pk = bdata[base + e];
    int tl = pk & 511;
    int pos = atomicAdd(&cur[tl], 1);
    if (pos < 8192) lds[pos] = (int)(pk >> 9);
  }
  __syncthreads();
  int len = re - rs;
  for (int j = t; j < len; j += 256) crow[rs + j] = lds[j];
}

// ---------------- transform: out[r,:] = dinv[r] * (in[r,:] @ W)  (MFMA, bf16)
// in: bf16 if (inbf || *flagp), else fp32 (converted inline).
__global__ __launch_bounds__(256) void k_xform(const void* __restrict__ in, int inbf,
                                               const int* __restrict__ flagp,
                                               const u16* __restrict__ wT,
                                               const float* __restrict__ dinv,
                                               u16* __restrict__ out, int N) {
  __shared__ __align__(16) u16 ws[64 * 72];
  int t = threadIdx.x;
  #pragma unroll
  for (int f = t; f < 512; f += 256) {
    int n = f >> 3, o = f & 7;
    *(float4*)&ws[n * 72 + o * 8] = ((const float4*)wT)[f];
  }
  __syncthreads();
  int fl = inbf ? 1 : *flagp;
  int lane = t & 63, wid = t >> 6;
  int g = lane >> 4, c = lane & 15;
  int arow = blockIdx.x * 64 + wid * 16 + c;
  short8 a0 = {0, 0, 0, 0, 0, 0, 0, 0}, a1 = {0, 0, 0, 0, 0, 0, 0, 0};
  if (arow < N) {
    if (fl) {
      const u16* p = (const u16*)in + (size_t)arow * 64 + g * 8;
      a0 = *(const short8*)p;
      a1 = *(const short8*)(p + 32);
    } else {
      const float* p = (const float*)in + (size_t)arow * 64 + g * 8;
      u16 tmp[16];
      #pragma unroll
      for (int j = 0; j < 8; j++) tmp[j] = f2bf(p[j]);
      #pragma unroll
      for (int j = 0; j < 8; j++) tmp[8 + j] = f2bf(p[32 + j]);
      a0 = *(short8*)tmp;
      a1 = *(short8*)(tmp + 8);
    }
  }
  int rbase = blockIdx.x * 64 + wid * 16 + g * 4;
  float dv[4];
  #pragma unroll
  for (int r = 0; r < 4; r++) dv[r] = (rbase + r < N) ? dinv[rbase + r] : 0.f;
  #pragma unroll
  for (int tile = 0; tile < 4; tile++) {
    short8 b0 = *(const short8*)&ws[(tile * 16 + c) * 72 + g * 8];
    short8 b1 = *(const short8*)&ws[(tile * 16 + c) * 72 + g * 8 + 32];
    f32x4 z = {0.f, 0.f, 0.f, 0.f};
    f32x4 acc = __builtin_amdgcn_mfma_f32_16x16x32_bf16(a0, b0, z, 0, 0, 0);
    acc = __builtin_amdgcn_mfma_f32_16x16x32_bf16(a1, b1, acc, 0, 0, 0);
    #pragma unroll
    for (int r = 0; r < 4; r++) {
      int orow = rbase + r;
      if (orow < N) out[(size_t)orow * 64 + tile * 16 + c] = f2bf(acc[r] * dv[r]);
    }
  }
}

// ---------------- aggregation: dst[i,:] = relu(dinv[i]*(sum of pre-scaled rows) + b)
__global__ __launch_bounds__(256) void k_agg(const u16* __restrict__ src, u16* __restrict__ dst,
                                             const int* __restrict__ csr_row,
                                             const int* __restrict__ csr_ptr,
                                             const int* __restrict__ deg,
                                             const float* __restrict__ dinv,
                                             const float* __restrict__ bias, int N) {
  int lane = threadIdx.x & 63;
  int wid = threadIdx.x >> 6;
  int i = blockIdx.x * 4 + wid;
  if (i >= N) return;
  int sub = lane >> 4;
  int fq  = lane & 15;
  int start = csr_ptr[i];
  int total = deg[i];
  const u16* base = src + (size_t)fq * 4;
  float a0 = 0.f, a1 = 0.f, a2 = 0.f, a3 = 0.f;
  #pragma unroll 2
  for (int t = sub; t < total; t += 4) {
    int r = (t == 0) ? i : csr_row[start + t - 1];
    uint2 v = *(const uint2*)(base + (size_t)r * 64);
    a0 += __uint_as_float(v.x << 16);
    a1 += __uint_as_float(v.x & 0xffff0000u);
    a2 += __uint_as_float(v.y << 16);
    a3 += __uint_as_float(v.y & 0xffff0000u);
  }
  a0 += __shfl_xor(a0, 16); a1 += __shfl_xor(a1, 16);
  a2 += __shfl_xor(a2, 16); a3 += __shfl_xor(a3, 16);
  a0 += __shfl_xor(a0, 32); a1 += __shfl_xor(a1, 32);
  a2 += __shfl_xor(a2, 32); a3 += __shfl_xor(a3, 32);
  if (sub == 0) {
    float di = dinv[i];
    float4 b4 = ((const float4*)bias)[fq];
    u16 o[4];
    o[0] = f2bf(fmaxf(fmaf(a0, di, b4.x), 0.f));
    o[1] = f2bf(fmaxf(fmaf(a1, di, b4.y), 0.f));
    o[2] = f2bf(fmaxf(fmaf(a2, di, b4.z), 0.f));
    o[3] = f2bf(fmaxf(fmaf(a3, di, b4.w), 0.f));
    *(uint2*)&dst[(size_t)i * 64 + fq * 4] = *(uint2*)o;
  }
}

// ----------------------------- fused fc1(relu)+fc2 + ssq via MFMA (wave = 16 nodes)
__global__ __launch_bounds__(256) void k_fc(const u16* __restrict__ h,
                                            const u16* __restrict__ fc1T,
                                            const float* __restrict__ wf,
                                            float* __restrict__ outf,
                                            float* __restrict__ ssum, int N) {
  __shared__ __align__(16) u16 ws[256 * 72];
  __shared__ float red[16];
  int t = threadIdx.x;
  #pragma unroll
  for (int f = t; f < 2048; f += 256) {
    int n = f >> 3, o = f & 7;
    *(float4*)&ws[n * 72 + o * 8] = ((const float4*)fc1T)[f];
  }
  __syncthreads();
  int lane = t & 63, wid = t >> 6;
  int g = lane >> 4, c = lane & 15;
  int arow = blockIdx.x * 64 + wid * 16 + c;
  short8 a0 = {0, 0, 0, 0, 0, 0, 0, 0}, a1 = {0, 0, 0, 0, 0, 0, 0, 0};
  if (arow < N) {
    a0 = *(const short8*)&h[(size_t)arow * 64 + g * 8];
    a1 = *(const short8*)&h[(size_t)arow * 64 + g * 8 + 32];
  }
  float psum[4] = {0.f, 0.f, 0.f, 0.f};
  #pragma unroll
  for (int tile = 0; tile < 16; tile++) {
    short8 b0 = *(const short8*)&ws[(tile * 16 + c) * 72 + g * 8];
    short8 b1 = *(const short8*)&ws[(tile * 16 + c) * 72 + g * 8 + 32];
    f32x4 z = {0.f, 0.f, 0.f, 0.f};
    f32x4 acc = __builtin_amdgcn_mfma_f32_16x16x32_bf16(a0, b0, z, 0, 0, 0);
    acc = __builtin_amdgcn_mfma_f32_16x16x32_bf16(a1, b1, acc, 0, 0, 0);
    int col = tile * 16 + c;
    float fb = wf[128 + col];
    float fw = wf[384 + col];
    #pragma unroll
    for (int r = 0; r < 4; r++) psum[r] += fmaxf(acc[r] + fb, 0.f) * fw;
  }
  #pragma unroll
  for (int off = 1; off < 16; off <<= 1) {
    #pragma unroll
    for (int r = 0; r < 4; r++) psum[r] += __shfl_xor(psum[r], off);
  }
  float fc2b = wf[640];
  if (c == 0) {
    float ss = 0.f;
    int rbase = blockIdx.x * 64 + wid * 16 + g * 4;
    #pragma unroll
    for (int r = 0; r < 4; r++) {
      int row = rbase + r;
      if (row < N) {
        float o = psum[r] + fc2b;
        outf[row] = o;
        ss += o * o;
      }
    }
    red[wid * 4 + g] = ss;
  }
  __syncthreads();
  if (t == 0) {
    float s = 0.f;
    #pragma unroll
    for (int j = 0; j < 16; j++) s += red[j];
    atomicAdd(ssum, s);
  }
}

// ------------------------------------------------------------- L2 norm write
__global__ void k_norm(const float* __restrict__ outf, const float* __restrict__ ssum,
                       void* dout, int N, const int* flag) {
  int i = blockIdx.x * blockDim.x + threadIdx.x;
  if (i >= N) return;
  float denom = fmaxf(sqrtf(*ssum), 1e-12f);
  float v = outf[i] / denom;
  if (*flag) ((__hip_bfloat16*)dout)[i] = __float2bfloat16(v);
  else       ((float*)dout)[i] = v;
}

extern "C" void kernel_launch(void* const* d_in, const int* in_sizes, int n_in,
                              void* d_out, int out_size, void* d_ws, size_t ws_size,
                              hipStream_t stream) {
  const void* x   = d_in[0];
  const int* eidx = (const int*)d_in[1];
  const void* W1  = d_in[2]; const void* b1  = d_in[3];
  const void* W2  = d_in[4]; const void* b2  = d_in[5];
  const void* f1w = d_in[6]; const void* f1b = d_in[7];
  const void* f2w = d_in[8]; const void* f2b = d_in[9];
  int N = in_sizes[0] / 64;
  int E = in_sizes[1] / 2;
  int npb = (N + 255) / 256;  // nodes per bucket

  char* ws = (char*)d_ws;
  size_t off = 0;
  auto alloc = [&](size_t b) {
    void* p = ws + off;
    off = (off + b + 255) & ~(size_t)255;
    return p;
  };
  int*   flag  = (int*)  alloc(4);
  float* ssum  = (float*)alloc(4);
  int*   bcnt  = (int*)  alloc(256 * 4);
  int*   bbase = (int*)  alloc(256 * 4);
  int*   bcur  = (int*)  alloc(256 * 4);
  u32*   bdata = (u32*)  alloc((size_t)E * 4);
  int*   deg   = (int*)  alloc((size_t)N * 4);
  int*   ptr   = (int*)  alloc((size_t)N * 4);
  int*   bsum  = (int*)  alloc(512 * 4);
  int*   bsum2 = (int*)  alloc(512 * 4);
  float* dinv  = (float*)alloc((size_t)N * 4);
  int*   crow  = (int*)  alloc((size_t)E * 4);
  u16*   wbh   = (u16*)  alloc(24576 * 2);
  float* wbf   = (float*)alloc(641 * 4);
  u16*   HA    = (u16*)  alloc((size_t)N * 64 * 2);
  u16*   HT    = (u16*)  alloc((size_t)N * 64 * 2);
  float* outf  = (float*)alloc((size_t)N * 4);

  int GN = (N + 255) / 256;
  int GEB = (E + 8191) / 8192;
  int NT = (N + 63) / 64;

  k_flag<<<1, 256, 0, stream>>>(x, flag, ssum, bcnt);
  k_conv_w<<<(24576 + 641 + 255) / 256, 256, 0, stream>>>(W1, b1, W2, b2, f1w, f1b, f2w, f2b,
                                                          wbh, wbf, flag);
  // CSR build (bucketed)
  k_bcount<<<GEB, 256, 0, stream>>>(eidx, E, npb, bcnt);
  k_bscan<<<1, 256, 0, stream>>>(bcnt, bbase, bcur);
  k_bfill<<<GEB, 256, 0, stream>>>(eidx, E, npb, bcur, bdata);
  k_degb<<<256, 256, 0, stream>>>(bdata, bbase, bcnt, deg, N, npb);
  k_scan_a<<<GN, 256, 0, stream>>>(deg, ptr, bsum, N);
  k_scan_b<<<1, 512, 0, stream>>>(bsum, bsum2, GN);
  k_scan_c<<<GN, 256, 0, stream>>>(ptr, bsum2, deg, dinv, N);
  k_p2<<<256, 256, 0, stream>>>(bdata, bbase, bcnt, ptr, crow, N, npb, E);

  // conv1 (reads raw x, converts inline)
  k_xform<<<NT, 256, 0, stream>>>(x, 0, flag, wbh + 0, dinv, HT, N);
  k_agg<<<(N + 3) / 4, 256, 0, stream>>>(HT, HA, crow, ptr, deg, dinv, wbf + 0, N);
  // conv2
  k_xform<<<NT, 256, 0, stream>>>(HA, 1, flag, wbh + 4096, dinv, HT, N);
  k_agg<<<(N + 3) / 4, 256, 0, stream>>>(HT, HA, crow, ptr, deg, dinv, wbf + 64, N);
  // fused MLP + sum of squares
  k_fc<<<NT, 256, 0, stream>>>(HA, wbh + 8192, wbf, outf, ssum, N);
  // normalize + write
  k_norm<<<GN, 256, 0, stream>>>(outf, ssum, d_out, N, flag);
}

// Round 5
// 295.131 us; speedup vs baseline: 3.5011x; 1.0787x over previous
//
#include <hip/hip_runtime.h>
#include <hip/hip_bf16.h>

typedef unsigned short u16;
typedef unsigned int u32;
typedef __attribute__((ext_vector_type(8))) short short8;
typedef __attribute__((ext_vector_type(4))) float f32x4;

__device__ __forceinline__ float bf2f(u16 h) {
  return __uint_as_float(((u32)h) << 16);
}
__device__ __forceinline__ float ldconv(const void* p, int i, int fl) {
  return fl ? bf2f(((const u16*)p)[i]) : ((const float*)p)[i];
}
__device__ __forceinline__ u16 f2bf(float v) {
  __hip_bfloat16 h = __float2bfloat16(v);
  return *(u16*)&h;
}

// ---------------------------------------------------------------- dtype sniff
__global__ void k_flag(const void* x, int* flag, float* ssum, int* bcnt) {
  __shared__ float red[256];
  int t = threadIdx.x;
  const u16* h = (const u16*)x;
  float m = 0.f;
  for (int i = t; i < 1024; i += 256) m = fmaxf(m, fabsf(bf2f(h[i])));
  red[t] = m; __syncthreads();
  for (int off = 128; off > 0; off >>= 1) {
    if (t < off) red[t] = fmaxf(red[t], red[t + off]);
    __syncthreads();
  }
  bcnt[t] = 0; bcnt[t + 256] = 0;
  if (t == 0) { *flag = (red[0] < 1000.0f) ? 1 : 0; *ssum = 0.f; }
}

// ------------------------------------------------------- weight conversion
// wbh (u16): W1T [0,4096) W2T [4096,8192) fc1T [8192,24576)   (all [n][k], k=64)
// wbf (f32): b1[0,64) b2[64,128) fc1b[128,384) fc2w[384,640) fc2b[640]
__global__ void k_conv_w(const void* W1, const void* b1, const void* W2, const void* b2,
                         const void* f1w, const void* f1b, const void* f2w, const void* f2b,
                         u16* wbh, float* wbf, const int* flag) {
  int fl = *flag;
  int i = blockIdx.x * blockDim.x + threadIdx.x;
  if (i < 4096) {
    int n = i >> 6, k = i & 63;
    wbh[i] = f2bf(ldconv(W1, k * 64 + n, fl));
  } else if (i < 8192) {
    int j = i - 4096; int n = j >> 6, k = j & 63;
    wbh[i] = f2bf(ldconv(W2, k * 64 + n, fl));
  } else if (i < 24576) {
    int j = i - 8192; int n = j >> 6, k = j & 63;
    wbh[i] = f2bf(ldconv(f1w, k * 256 + n, fl));
  } else if (i < 24576 + 641) {
    int j = i - 24576;
    float v;
    if (j < 64)       v = ldconv(b1,  j,       fl);
    else if (j < 128) v = ldconv(b2,  j - 64,  fl);
    else if (j < 384) v = ldconv(f1b, j - 128, fl);
    else if (j < 640) v = ldconv(f2w, j - 384, fl);
    else              v = ldconv(f2b, 0,       fl);
    wbf[j] = v;
  }
}

// --------------------------------------- bucketed CSR build (256-node buckets)
// Pass A: per-block LDS histogram; save per-block hist + accumulate totals.
__global__ __launch_bounds__(256) void k_bcount(const int* __restrict__ eidx, int E,
                                                int* bcnt, int* blockhist) {
  __shared__ int hist[512];
  int t = threadIdx.x;
  hist[t] = 0; hist[t + 256] = 0;
  __syncthreads();
  int e0 = blockIdx.x * 8192;
  int e1 = min(e0 + 8192, E);
  for (int e = e0 + t; e < e1; e += 256) atomicAdd(&hist[eidx[E + e] >> 8], 1);
  __syncthreads();
  int* bh = blockhist + blockIdx.x * 512;
  for (int j = t; j < 512; j += 256) {
    bh[j] = hist[j];
    if (hist[j]) atomicAdd(&bcnt[j], hist[j]);
  }
}

// exclusive scan of bucket counts -> bbase (persist) and bcur (running)
__global__ void k_bscan(const int* __restrict__ bcnt, int* bbase, int* bcur) {
  __shared__ int tmp[512];
  int t = threadIdx.x;
  int v = bcnt[t];
  tmp[t] = v; __syncthreads();
  for (int off = 1; off < 512; off <<= 1) {
    int u = (t >= off) ? tmp[t - off] : 0;
    __syncthreads();
    tmp[t] += u;
    __syncthreads();
  }
  bbase[t] = tmp[t] - v;
  bcur[t]  = tmp[t] - v;
}

// Pass B: reserve per-(block,bucket) runs using saved hist, scatter packed edges.
__global__ __launch_bounds__(256) void k_bfill(const int* __restrict__ eidx, int E,
                                               const int* __restrict__ blockhist,
                                               int* bcur, u32* bdata) {
  __shared__ int base[512];
  __shared__ int hist[512];
  int t = threadIdx.x;
  const int* bh = blockhist + blockIdx.x * 512;
  for (int j = t; j < 512; j += 256) {
    int c = bh[j];
    base[j] = c ? atomicAdd(&bcur[j], c) : 0;
    hist[j] = 0;
  }
  __syncthreads();
  int e0 = blockIdx.x * 8192;
  int e1 = min(e0 + 8192, E);
  for (int e = e0 + t; e < e1; e += 256) {
    int src = eidx[e];
    int tgt = eidx[E + e];
    int b = tgt >> 8;
    int idx = atomicAdd(&hist[b], 1);
    bdata[base[b] + idx] = ((u32)src << 8) | (u32)(tgt & 255);
  }
}

// One block per bucket: histogram -> deg/dinv/ptr, LDS scan, LDS scatter, seq write.
__global__ __launch_bounds__(256) void k_csr(const u32* __restrict__ bdata,
                                             const int* __restrict__ bbase,
                                             const int* __restrict__ bcnt,
                                             int* __restrict__ deg, float* __restrict__ dinv,
                                             int* __restrict__ ptr, int* __restrict__ crow,
                                             int N) {
  __shared__ int lds[8192];
  __shared__ int hist[256];
  __shared__ int tmp[256];
  __shared__ int cur[256];
  int b = blockIdx.x, t = threadIdx.x;
  int node0 = b << 8;
  int ncnt = min(256, N - node0);
  hist[t] = 0;
  __syncthreads();
  int base = bbase[b], cnt = bcnt[b];
  for (int e = t; e < cnt; e += 256) atomicAdd(&hist[bdata[base + e] & 255], 1);
  __syncthreads();
  int h = hist[t];
  if (t < ncnt) {
    deg[node0 + t] = h + 1;
    dinv[node0 + t] = 1.0f / sqrtf((float)(h + 1));
  }
  tmp[t] = h; __syncthreads();
  for (int off = 1; off < 256; off <<= 1) {
    int u = (t >= off) ? tmp[t - off] : 0;
    __syncthreads();
    tmp[t] += u;
    __syncthreads();
  }
  int excl = tmp[t] - h;
  if (t < ncnt) ptr[node0 + t] = base + excl;
  cur[t] = excl;
  __syncthreads();
  for (int e = t; e < cnt; e += 256) {
    u32 pk = bdata[base + e];
    int pos = atomicAdd(&cur[pk & 255], 1);
    if (pos < 8192) lds[pos] = (int)(pk >> 8);
  }
  __syncthreads();
  for (int j = t; j < cnt; j += 256) crow[base + j] = lds[j];
}

// ---------------- transform: out[r,:] = dinv[r] * (in[r,:] @ W)  (MFMA, bf16)
__global__ __launch_bounds__(256) void k_xform(const void* __restrict__ in, int inbf,
                                               const int* __restrict__ flagp,
                                               const u16* __restrict__ wT,
                                               const float* __restrict__ dinv,
                                               u16* __restrict__ out, int N) {
  __shared__ __align__(16) u16 ws[64 * 72];
  int t = threadIdx.x;
  #pragma unroll
  for (int f = t; f < 512; f += 256) {
    int n = f >> 3, o = f & 7;
    *(float4*)&ws[n * 72 + o * 8] = ((const float4*)wT)[f];
  }
  __syncthreads();
  int fl = inbf ? 1 : *flagp;
  int lane = t & 63, wid = t >> 6;
  int g = lane >> 4, c = lane & 15;
  int arow = blockIdx.x * 64 + wid * 16 + c;
  short8 a0 = {0, 0, 0, 0, 0, 0, 0, 0}, a1 = {0, 0, 0, 0, 0, 0, 0, 0};
  if (arow < N) {
    if (fl) {
      const u16* p = (const u16*)in + (size_t)arow * 64 + g * 8;
      a0 = *(const short8*)p;
      a1 = *(const short8*)(p + 32);
    } else {
      const float* p = (const float*)in + (size_t)arow * 64 + g * 8;
      u16 tmpv[16];
      #pragma unroll
      for (int j = 0; j < 8; j++) tmpv[j] = f2bf(p[j]);
      #pragma unroll
      for (int j = 0; j < 8; j++) tmpv[8 + j] = f2bf(p[32 + j]);
      a0 = *(short8*)tmpv;
      a1 = *(short8*)(tmpv + 8);
    }
  }
  int rbase = blockIdx.x * 64 + wid * 16 + g * 4;
  float dv[4];
  #pragma unroll
  for (int r = 0; r < 4; r++) dv[r] = (rbase + r < N) ? dinv[rbase + r] : 0.f;
  #pragma unroll
  for (int tile = 0; tile < 4; tile++) {
    short8 b0 = *(const short8*)&ws[(tile * 16 + c) * 72 + g * 8];
    short8 b1 = *(const short8*)&ws[(tile * 16 + c) * 72 + g * 8 + 32];
    f32x4 z = {0.f, 0.f, 0.f, 0.f};
    f32x4 acc = __builtin_amdgcn_mfma_f32_16x16x32_bf16(a0, b0, z, 0, 0, 0);
    acc = __builtin_amdgcn_mfma_f32_16x16x32_bf16(a1, b1, acc, 0, 0, 0);
    #pragma unroll
    for (int r = 0; r < 4; r++) {
      int orow = rbase + r;
      if (orow < N) out[(size_t)orow * 64 + tile * 16 + c] = f2bf(acc[r] * dv[r]);
    }
  }
}

// ---------------- aggregation: dst[i,:] = relu(dinv[i]*(sum of pre-scaled rows) + b)
// wave = 1 node; 4 subgroups of 16 lanes; unroll 4 -> 4 gather chains in flight.
__global__ __launch_bounds__(256) void k_agg(const u16* __restrict__ src, u16* __restrict__ dst,
                                             const int* __restrict__ csr_row,
                                             const int* __restrict__ csr_ptr,
                                             const int* __restrict__ deg,
                                             const float* __restrict__ dinv,
                                             const float* __restrict__ bias, int N) {
  int lane = threadIdx.x & 63;
  int wid = threadIdx.x >> 6;
  int i = blockIdx.x * 4 + wid;
  if (i >= N) return;
  int sub = lane >> 4;
  int fq  = lane & 15;
  int start = csr_ptr[i];
  int total = deg[i];
  const u16* base = src + (size_t)fq * 4;
  float a0 = 0.f, a1 = 0.f, a2 = 0.f, a3 = 0.f;
  #pragma unroll 4
  for (int t = sub; t < total; t += 4) {
    int r = (t == 0) ? i : csr_row[start + t - 1];
    uint2 v = *(const uint2*)(base + (size_t)r * 64);
    a0 += __uint_as_float(v.x << 16);
    a1 += __uint_as_float(v.x & 0xffff0000u);
    a2 += __uint_as_float(v.y << 16);
    a3 += __uint_as_float(v.y & 0xffff0000u);
  }
  a0 += __shfl_xor(a0, 16); a1 += __shfl_xor(a1, 16);
  a2 += __shfl_xor(a2, 16); a3 += __shfl_xor(a3, 16);
  a0 += __shfl_xor(a0, 32); a1 += __shfl_xor(a1, 32);
  a2 += __shfl_xor(a2, 32); a3 += __shfl_xor(a3, 32);
  if (sub == 0) {
    float di = dinv[i];
    float4 b4 = ((const float4*)bias)[fq];
    u16 o[4];
    o[0] = f2bf(fmaxf(fmaf(a0, di, b4.x), 0.f));
    o[1] = f2bf(fmaxf(fmaf(a1, di, b4.y), 0.f));
    o[2] = f2bf(fmaxf(fmaf(a2, di, b4.z), 0.f));
    o[3] = f2bf(fmaxf(fmaf(a3, di, b4.w), 0.f));
    *(uint2*)&dst[(size_t)i * 64 + fq * 4] = *(uint2*)o;
  }
}

// ----------------------------- fused fc1(relu)+fc2 + ssq via MFMA (wave = 16 nodes)
__global__ __launch_bounds__(256) void k_fc(const u16* __restrict__ h,
                                            const u16* __restrict__ fc1T,
                                            const float* __restrict__ wf,
                                            float* __restrict__ outf,
                                            float* __restrict__ ssum, int N) {
  __shared__ __align__(16) u16 ws[256 * 72];
  __shared__ float red[16];
  int t = threadIdx.x;
  #pragma unroll
  for (int f = t; f < 2048; f += 256) {
    int n = f >> 3, o = f & 7;
    *(float4*)&ws[n * 72 + o * 8] = ((const float4*)fc1T)[f];
  }
  __syncthreads();
  int lane = t & 63, wid = t >> 6;
  int g = lane >> 4, c = lane & 15;
  int arow = blockIdx.x * 64 + wid * 16 + c;
  short8 a0 = {0, 0, 0, 0, 0, 0, 0, 0}, a1 = {0, 0, 0, 0, 0, 0, 0, 0};
  if (arow < N) {
    a0 = *(const short8*)&h[(size_t)arow * 64 + g * 8];
    a1 = *(const short8*)&h[(size_t)arow * 64 + g * 8 + 32];
  }
  float psum[4] = {0.f, 0.f, 0.f, 0.f};
  #pragma unroll
  for (int tile = 0; tile < 16; tile++) {
    short8 b0 = *(const short8*)&ws[(tile * 16 + c) * 72 + g * 8];
    short8 b1 = *(const short8*)&ws[(tile * 16 + c) * 72 + g * 8 + 32];
    f32x4 z = {0.f, 0.f, 0.f, 0.f};
    f32x4 acc = __builtin_amdgcn_mfma_f32_16x16x32_bf16(a0, b0, z, 0, 0, 0);
    acc = __builtin_amdgcn_mfma_f32_16x16x32_bf16(a1, b1, acc, 0, 0, 0);
    int col = tile * 16 + c;
    float fb = wf[128 + col];
    float fw = wf[384 + col];
    #pragma unroll
    for (int r = 0; r < 4; r++) psum[r] += fmaxf(acc[r] + fb, 0.f) * fw;
  }
  #pragma unroll
  for (int off = 1; off < 16; off <<= 1) {
    #pragma unroll
    for (int r = 0; r < 4; r++) psum[r] += __shfl_xor(psum[r], off);
  }
  float fc2b = wf[640];
  if (c == 0) {
    float ss = 0.f;
    int rbase = blockIdx.x * 64 + wid * 16 + g * 4;
    #pragma unroll
    for (int r = 0; r < 4; r++) {
      int row = rbase + r;
      if (row < N) {
        float o = psum[r] + fc2b;
        outf[row] = o;
        ss += o * o;
      }
    }
    red[wid * 4 + g] = ss;
  }
  __syncthreads();
  if (t == 0) {
    float s = 0.f;
    #pragma unroll
    for (int j = 0; j < 16; j++) s += red[j];
    atomicAdd(ssum, s);
  }
}

// ------------------------------------------------------------- L2 norm write
__global__ void k_norm(const float* __restrict__ outf, const float* __restrict__ ssum,
                       void* dout, int N, const int* flag) {
  int i = blockIdx.x * blockDim.x + threadIdx.x;
  if (i >= N) return;
  float denom = fmaxf(sqrtf(*ssum), 1e-12f);
  float v = outf[i] / denom;
  if (*flag) ((__hip_bfloat16*)dout)[i] = __float2bfloat16(v);
  else       ((float*)dout)[i] = v;
}

extern "C" void kernel_launch(void* const* d_in, const int* in_sizes, int n_in,
                              void* d_out, int out_size, void* d_ws, size_t ws_size,
                              hipStream_t stream) {
  const void* x   = d_in[0];
  const int* eidx = (const int*)d_in[1];
  const void* W1  = d_in[2]; const void* b1  = d_in[3];
  const void* W2  = d_in[4]; const void* b2  = d_in[5];
  const void* f1w = d_in[6]; const void* f1b = d_in[7];
  const void* f2w = d_in[8]; const void* f2b = d_in[9];
  int N = in_sizes[0] / 64;
  int E = in_sizes[1] / 2;
  int NB = (N + 255) >> 8;           // 256-node buckets
  int GEB = (E + 8191) / 8192;

  char* ws = (char*)d_ws;
  size_t off = 0;
  auto alloc = [&](size_t b) {
    void* p = ws + off;
    off = (off + b + 255) & ~(size_t)255;
    return p;
  };
  int*   flag  = (int*)  alloc(4);
  float* ssum  = (float*)alloc(4);
  int*   bcnt  = (int*)  alloc(512 * 4);
  int*   bbase = (int*)  alloc(512 * 4);
  int*   bcur  = (int*)  alloc(512 * 4);
  int*   bhist = (int*)  alloc((size_t)GEB * 512 * 4);
  u32*   bdata = (u32*)  alloc((size_t)E * 4);
  int*   deg   = (int*)  alloc((size_t)N * 4);
  int*   ptr   = (int*)  alloc((size_t)N * 4);
  float* dinv  = (float*)alloc((size_t)N * 4);
  int*   crow  = (int*)  alloc((size_t)E * 4);
  u16*   wbh   = (u16*)  alloc(24576 * 2);
  float* wbf   = (float*)alloc(641 * 4);
  u16*   HA    = (u16*)  alloc((size_t)N * 64 * 2);
  u16*   HT    = (u16*)  alloc((size_t)N * 64 * 2);
  float* outf  = (float*)alloc((size_t)N * 4);

  int GN = (N + 255) / 256;
  int NT = (N + 63) / 64;

  k_flag<<<1, 256, 0, stream>>>(x, flag, ssum, bcnt);
  k_conv_w<<<(24576 + 641 + 255) / 256, 256, 0, stream>>>(W1, b1, W2, b2, f1w, f1b, f2w, f2b,
                                                          wbh, wbf, flag);
  // CSR build (bucketed, 256-node buckets)
  k_bcount<<<GEB, 256, 0, stream>>>(eidx, E, bcnt, bhist);
  k_bscan<<<1, 512, 0, stream>>>(bcnt, bbase, bcur);
  k_bfill<<<GEB, 256, 0, stream>>>(eidx, E, bhist, bcur, bdata);
  k_csr<<<NB, 256, 0, stream>>>(bdata, bbase, bcnt, deg, dinv, ptr, crow, N);

  // conv1 (reads raw x, converts inline)
  k_xform<<<NT, 256, 0, stream>>>(x, 0, flag, wbh + 0, dinv, HT, N);
  k_agg<<<(N + 3) / 4, 256, 0, stream>>>(HT, HA, crow, ptr, deg, dinv, wbf + 0, N);
  // conv2
  k_xform<<<NT, 256, 0, stream>>>(HA, 1, flag, wbh + 4096, dinv, HT, N);
  k_agg<<<(N + 3) / 4, 256, 0, stream>>>(HT, HA, crow, ptr, deg, dinv, wbf + 64, N);
  // fused MLP + sum of squares
  k_fc<<<NT, 256, 0, stream>>>(HA, wbh + 8192, wbf, outf, ssum, N);
  // normalize + write
  k_norm<<<GN, 256, 0, stream>>>(outf, ssum, d_out, N, flag);
}

// Round 6
// 290.211 us; speedup vs baseline: 3.5605x; 1.0170x over previous
//
#include <hip/hip_runtime.h>
#include <hip/hip_bf16.h>

typedef unsigned short u16;
typedef unsigned int u32;
typedef __attribute__((ext_vector_type(8))) short short8;
typedef __attribute__((ext_vector_type(4))) float f32x4;

__device__ __forceinline__ float bf2f(u16 h) {
  return __uint_as_float(((u32)h) << 16);
}
__device__ __forceinline__ float ldconv(const void* p, int i, int fl) {
  return fl ? bf2f(((const u16*)p)[i]) : ((const float*)p)[i];
}
__device__ __forceinline__ u16 f2bf(float v) {
  __hip_bfloat16 h = __float2bfloat16(v);
  return *(u16*)&h;
}

// ---------------------------------------------------------------- dtype sniff
__global__ void k_flag(const void* x, int* flag, float* ssum, int* bcnt) {
  __shared__ float red[256];
  int t = threadIdx.x;
  const u16* h = (const u16*)x;
  float m = 0.f;
  for (int i = t; i < 1024; i += 256) m = fmaxf(m, fabsf(bf2f(h[i])));
  red[t] = m; __syncthreads();
  for (int off = 128; off > 0; off >>= 1) {
    if (t < off) red[t] = fmaxf(red[t], red[t + off]);
    __syncthreads();
  }
  bcnt[t] = 0; bcnt[t + 256] = 0;
  if (t == 0) { *flag = (red[0] < 1000.0f) ? 1 : 0; *ssum = 0.f; }
}

// ------------------------------------------------------- weight conversion
// wbh (u16): W1T [0,4096) W2T [4096,8192) fc1T [8192,24576)   (all [n][k], k=64)
// wbf (f32): b1[0,64) b2[64,128) fc1b[128,384) fc2w[384,640) fc2b[640]
__global__ void k_conv_w(const void* W1, const void* b1, const void* W2, const void* b2,
                         const void* f1w, const void* f1b, const void* f2w, const void* f2b,
                         u16* wbh, float* wbf, const int* flag) {
  int fl = *flag;
  int i = blockIdx.x * blockDim.x + threadIdx.x;
  if (i < 4096) {
    int n = i >> 6, k = i & 63;
    wbh[i] = f2bf(ldconv(W1, k * 64 + n, fl));
  } else if (i < 8192) {
    int j = i - 4096; int n = j >> 6, k = j & 63;
    wbh[i] = f2bf(ldconv(W2, k * 64 + n, fl));
  } else if (i < 24576) {
    int j = i - 8192; int n = j >> 6, k = j & 63;
    wbh[i] = f2bf(ldconv(f1w, k * 256 + n, fl));
  } else if (i < 24576 + 641) {
    int j = i - 24576;
    float v;
    if (j < 64)       v = ldconv(b1,  j,       fl);
    else if (j < 128) v = ldconv(b2,  j - 64,  fl);
    else if (j < 384) v = ldconv(f1b, j - 128, fl);
    else if (j < 640) v = ldconv(f2w, j - 384, fl);
    else              v = ldconv(f2b, 0,       fl);
    wbf[j] = v;
  }
}

// --------------------------------------- bucketed CSR build (256-node buckets)
__global__ __launch_bounds__(256) void k_bcount(const int* __restrict__ eidx, int E,
                                                int* bcnt, int* blockhist) {
  __shared__ int hist[512];
  int t = threadIdx.x;
  hist[t] = 0; hist[t + 256] = 0;
  __syncthreads();
  int e0 = blockIdx.x * 8192;
  int e1 = min(e0 + 8192, E);
  for (int e = e0 + t; e < e1; e += 256) atomicAdd(&hist[eidx[E + e] >> 8], 1);
  __syncthreads();
  int* bh = blockhist + blockIdx.x * 512;
  for (int j = t; j < 512; j += 256) {
    bh[j] = hist[j];
    if (hist[j]) atomicAdd(&bcnt[j], hist[j]);
  }
}

__global__ void k_bscan(const int* __restrict__ bcnt, int* bbase, int* bcur) {
  __shared__ int tmp[512];
  int t = threadIdx.x;
  int v = bcnt[t];
  tmp[t] = v; __syncthreads();
  for (int off = 1; off < 512; off <<= 1) {
    int u = (t >= off) ? tmp[t - off] : 0;
    __syncthreads();
    tmp[t] += u;
    __syncthreads();
  }
  bbase[t] = tmp[t] - v;
  bcur[t]  = tmp[t] - v;
}

__global__ __launch_bounds__(256) void k_bfill(const int* __restrict__ eidx, int E,
                                               const int* __restrict__ blockhist,
                                               int* bcur, u32* bdata) {
  __shared__ int base[512];
  __shared__ int hist[512];
  int t = threadIdx.x;
  const int* bh = blockhist + blockIdx.x * 512;
  for (int j = t; j < 512; j += 256) {
    int c = bh[j];
    base[j] = c ? atomicAdd(&bcur[j], c) : 0;
    hist[j] = 0;
  }
  __syncthreads();
  int e0 = blockIdx.x * 8192;
  int e1 = min(e0 + 8192, E);
  for (int e = e0 + t; e < e1; e += 256) {
    int src = eidx[e];
    int tgt = eidx[E + e];
    int b = tgt >> 8;
    int idx = atomicAdd(&hist[b], 1);
    bdata[base[b] + idx] = ((u32)src << 8) | (u32)(tgt & 255);
  }
}

// One block per bucket: histogram -> deg/dinv/ptr, LDS scan, LDS scatter, seq write.
__global__ __launch_bounds__(256) void k_csr(const u32* __restrict__ bdata,
                                             const int* __restrict__ bbase,
                                             const int* __restrict__ bcnt,
                                             int* __restrict__ deg, float* __restrict__ dinv,
                                             int* __restrict__ ptr, int* __restrict__ crow,
                                             int N) {
  __shared__ int lds[8192];
  __shared__ int hist[256];
  __shared__ int tmp[256];
  __shared__ int cur[256];
  int b = blockIdx.x, t = threadIdx.x;
  int node0 = b << 8;
  int ncnt = min(256, N - node0);
  hist[t] = 0;
  __syncthreads();
  int base = bbase[b], cnt = bcnt[b];
  for (int e = t; e < cnt; e += 256) atomicAdd(&hist[bdata[base + e] & 255], 1);
  __syncthreads();
  int h = hist[t];
  if (t < ncnt) {
    deg[node0 + t] = h + 1;
    dinv[node0 + t] = 1.0f / sqrtf((float)(h + 1));
  }
  tmp[t] = h; __syncthreads();
  for (int off = 1; off < 256; off <<= 1) {
    int u = (t >= off) ? tmp[t - off] : 0;
    __syncthreads();
    tmp[t] += u;
    __syncthreads();
  }
  int excl = tmp[t] - h;
  if (t < ncnt) ptr[node0 + t] = base + excl;
  cur[t] = excl;
  __syncthreads();
  for (int e = t; e < cnt; e += 256) {
    u32 pk = bdata[base + e];
    int pos = atomicAdd(&cur[pk & 255], 1);
    if (pos < 8192) lds[pos] = (int)(pk >> 8);
  }
  __syncthreads();
  for (int j = t; j < cnt; j += 256) crow[base + j] = lds[j];
}

// ---------------- transform: out[r,:] = dinv[r] * (in[r,:] @ W)  (MFMA, bf16)
__global__ __launch_bounds__(256) void k_xform(const void* __restrict__ in, int inbf,
                                               const int* __restrict__ flagp,
                                               const u16* __restrict__ wT,
                                               const float* __restrict__ dinv,
                                               u16* __restrict__ out, int N) {
  __shared__ __align__(16) u16 ws[64 * 72];
  int t = threadIdx.x;
  #pragma unroll
  for (int f = t; f < 512; f += 256) {
    int n = f >> 3, o = f & 7;
    *(float4*)&ws[n * 72 + o * 8] = ((const float4*)wT)[f];
  }
  __syncthreads();
  int fl = inbf ? 1 : *flagp;
  int lane = t & 63, wid = t >> 6;
  int g = lane >> 4, c = lane & 15;
  int arow = blockIdx.x * 64 + wid * 16 + c;
  short8 a0 = {0, 0, 0, 0, 0, 0, 0, 0}, a1 = {0, 0, 0, 0, 0, 0, 0, 0};
  if (arow < N) {
    if (fl) {
      const u16* p = (const u16*)in + (size_t)arow * 64 + g * 8;
      a0 = *(const short8*)p;
      a1 = *(const short8*)(p + 32);
    } else {
      const float* p = (const float*)in + (size_t)arow * 64 + g * 8;
      u16 tmpv[16];
      #pragma unroll
      for (int j = 0; j < 8; j++) tmpv[j] = f2bf(p[j]);
      #pragma unroll
      for (int j = 0; j < 8; j++) tmpv[8 + j] = f2bf(p[32 + j]);
      a0 = *(short8*)tmpv;
      a1 = *(short8*)(tmpv + 8);
    }
  }
  int rbase = blockIdx.x * 64 + wid * 16 + g * 4;
  float dv[4];
  #pragma unroll
  for (int r = 0; r < 4; r++) dv[r] = (rbase + r < N) ? dinv[rbase + r] : 0.f;
  #pragma unroll
  for (int tile = 0; tile < 4; tile++) {
    short8 b0 = *(const short8*)&ws[(tile * 16 + c) * 72 + g * 8];
    short8 b1 = *(const short8*)&ws[(tile * 16 + c) * 72 + g * 8 + 32];
    f32x4 z = {0.f, 0.f, 0.f, 0.f};
    f32x4 acc = __builtin_amdgcn_mfma_f32_16x16x32_bf16(a0, b0, z, 0, 0, 0);
    acc = __builtin_amdgcn_mfma_f32_16x16x32_bf16(a1, b1, acc, 0, 0, 0);
    #pragma unroll
    for (int r = 0; r < 4; r++) {
      int orow = rbase + r;
      if (orow < N) out[(size_t)orow * 64 + tile * 16 + c] = f2bf(acc[r] * dv[r]);
    }
  }
}

// ---------------- aggregation: dst[i,:] = relu(dinv[i]*(sum of pre-scaled rows) + b)
// wave = 1 node; 8 subgroups of 8 lanes; lane loads uint4 (8 bf16 feats).
// One wave-wide load = 8 edges (1024 B); unroll 4 covers the degree tail.
__global__ __launch_bounds__(256) void k_agg(const u16* __restrict__ src, u16* __restrict__ dst,
                                             const int* __restrict__ csr_row,
                                             const int* __restrict__ csr_ptr,
                                             const int* __restrict__ deg,
                                             const float* __restrict__ dinv,
                                             const float* __restrict__ bias, int N) {
  int lane = threadIdx.x & 63;
  int wid = threadIdx.x >> 6;
  int i = blockIdx.x * 4 + wid;
  if (i >= N) return;
  int sub = lane >> 3;                 // 0..7: edge slot
  int fo  = lane & 7;                  // feature octet: feats 8*fo .. 8*fo+7
  int start = csr_ptr[i];
  int total = deg[i];
  const u16* base = src + (size_t)fo * 8;
  float a0 = 0.f, a1 = 0.f, a2 = 0.f, a3 = 0.f;
  float a4 = 0.f, a5 = 0.f, a6 = 0.f, a7 = 0.f;
  #pragma unroll 4
  for (int t = sub; t < total; t += 8) {
    int r = (t == 0) ? i : csr_row[start + t - 1];
    uint4 v = *(const uint4*)(base + (size_t)r * 64);
    a0 += __uint_as_float(v.x << 16);
    a1 += __uint_as_float(v.x & 0xffff0000u);
    a2 += __uint_as_float(v.y << 16);
    a3 += __uint_as_float(v.y & 0xffff0000u);
    a4 += __uint_as_float(v.z << 16);
    a5 += __uint_as_float(v.z & 0xffff0000u);
    a6 += __uint_as_float(v.w << 16);
    a7 += __uint_as_float(v.w & 0xffff0000u);
  }
  #pragma unroll
  for (int off = 8; off < 64; off <<= 1) {
    a0 += __shfl_xor(a0, off); a1 += __shfl_xor(a1, off);
    a2 += __shfl_xor(a2, off); a3 += __shfl_xor(a3, off);
    a4 += __shfl_xor(a4, off); a5 += __shfl_xor(a5, off);
    a6 += __shfl_xor(a6, off); a7 += __shfl_xor(a7, off);
  }
  if (sub == 0) {
    float di = dinv[i];
    float4 b0 = ((const float4*)bias)[2 * fo];
    float4 b1 = ((const float4*)bias)[2 * fo + 1];
    u16 o[8];
    o[0] = f2bf(fmaxf(fmaf(a0, di, b0.x), 0.f));
    o[1] = f2bf(fmaxf(fmaf(a1, di, b0.y), 0.f));
    o[2] = f2bf(fmaxf(fmaf(a2, di, b0.z), 0.f));
    o[3] = f2bf(fmaxf(fmaf(a3, di, b0.w), 0.f));
    o[4] = f2bf(fmaxf(fmaf(a4, di, b1.x), 0.f));
    o[5] = f2bf(fmaxf(fmaf(a5, di, b1.y), 0.f));
    o[6] = f2bf(fmaxf(fmaf(a6, di, b1.z), 0.f));
    o[7] = f2bf(fmaxf(fmaf(a7, di, b1.w), 0.f));
    *(uint4*)&dst[(size_t)i * 64 + fo * 8] = *(uint4*)o;
  }
}

// ----------------------------- fused fc1(relu)+fc2 + ssq via MFMA (wave = 16 nodes)
__global__ __launch_bounds__(256) void k_fc(const u16* __restrict__ h,
                                            const u16* __restrict__ fc1T,
                                            const float* __restrict__ wf,
                                            float* __restrict__ outf,
                                            float* __restrict__ ssum, int N) {
  __shared__ __align__(16) u16 ws[256 * 72];
  __shared__ float red[16];
  int t = threadIdx.x;
  #pragma unroll
  for (int f = t; f < 2048; f += 256) {
    int n = f >> 3, o = f & 7;
    *(float4*)&ws[n * 72 + o * 8] = ((const float4*)fc1T)[f];
  }
  __syncthreads();
  int lane = t & 63, wid = t >> 6;
  int g = lane >> 4, c = lane & 15;
  int arow = blockIdx.x * 64 + wid * 16 + c;
  short8 a0 = {0, 0, 0, 0, 0, 0, 0, 0}, a1 = {0, 0, 0, 0, 0, 0, 0, 0};
  if (arow < N) {
    a0 = *(const short8*)&h[(size_t)arow * 64 + g * 8];
    a1 = *(const short8*)&h[(size_t)arow * 64 + g * 8 + 32];
  }
  float psum[4] = {0.f, 0.f, 0.f, 0.f};
  #pragma unroll
  for (int tile = 0; tile < 16; tile++) {
    short8 b0 = *(const short8*)&ws[(tile * 16 + c) * 72 + g * 8];
    short8 b1 = *(const short8*)&ws[(tile * 16 + c) * 72 + g * 8 + 32];
    f32x4 z = {0.f, 0.f, 0.f, 0.f};
    f32x4 acc = __builtin_amdgcn_mfma_f32_16x16x32_bf16(a0, b0, z, 0, 0, 0);
    acc = __builtin_amdgcn_mfma_f32_16x16x32_bf16(a1, b1, acc, 0, 0, 0);
    int col = tile * 16 + c;
    float fb = wf[128 + col];
    float fw = wf[384 + col];
    #pragma unroll
    for (int r = 0; r < 4; r++) psum[r] += fmaxf(acc[r] + fb, 0.f) * fw;
  }
  #pragma unroll
  for (int off = 1; off < 16; off <<= 1) {
    #pragma unroll
    for (int r = 0; r < 4; r++) psum[r] += __shfl_xor(psum[r], off);
  }
  float fc2b = wf[640];
  if (c == 0) {
    float ss = 0.f;
    int rbase = blockIdx.x * 64 + wid * 16 + g * 4;
    #pragma unroll
    for (int r = 0; r < 4; r++) {
      int row = rbase + r;
      if (row < N) {
        float o = psum[r] + fc2b;
        outf[row] = o;
        ss += o * o;
      }
    }
    red[wid * 4 + g] = ss;
  }
  __syncthreads();
  if (t == 0) {
    float s = 0.f;
    #pragma unroll
    for (int j = 0; j < 16; j++) s += red[j];
    atomicAdd(ssum, s);
  }
}

// ------------------------------------------------------------- L2 norm write
__global__ void k_norm(const float* __restrict__ outf, const float* __restrict__ ssum,
                       void* dout, int N, const int* flag) {
  int i = blockIdx.x * blockDim.x + threadIdx.x;
  if (i >= N) return;
  float denom = fmaxf(sqrtf(*ssum), 1e-12f);
  float v = outf[i] / denom;
  if (*flag) ((__hip_bfloat16*)dout)[i] = __float2bfloat16(v);
  else       ((float*)dout)[i] = v;
}

extern "C" void kernel_launch(void* const* d_in, const int* in_sizes, int n_in,
                              void* d_out, int out_size, void* d_ws, size_t ws_size,
                              hipStream_t stream) {
  const void* x   = d_in[0];
  const int* eidx = (const int*)d_in[1];
  const void* W1  = d_in[2]; const void* b1  = d_in[3];
  const void* W2  = d_in[4]; const void* b2  = d_in[5];
  const void* f1w = d_in[6]; const void* f1b = d_in[7];
  const void* f2w = d_in[8]; const void* f2b = d_in[9];
  int N = in_sizes[0] / 64;
  int E = in_sizes[1] / 2;
  int NB = (N + 255) >> 8;           // 256-node buckets
  int GEB = (E + 8191) / 8192;

  char* ws = (char*)d_ws;
  size_t off = 0;
  auto alloc = [&](size_t b) {
    void* p = ws + off;
    off = (off + b + 255) & ~(size_t)255;
    return p;
  };
  int*   flag  = (int*)  alloc(4);
  float* ssum  = (float*)alloc(4);
  int*   bcnt  = (int*)  alloc(512 * 4);
  int*   bbase = (int*)  alloc(512 * 4);
  int*   bcur  = (int*)  alloc(512 * 4);
  int*   bhist = (int*)  alloc((size_t)GEB * 512 * 4);
  u32*   bdata = (u32*)  alloc((size_t)E * 4);
  int*   deg   = (int*)  alloc((size_t)N * 4);
  int*   ptr   = (int*)  alloc((size_t)N * 4);
  float* dinv  = (float*)alloc((size_t)N * 4);
  int*   crow  = (int*)  alloc((size_t)E * 4);
  u16*   wbh   = (u16*)  alloc(24576 * 2);
  float* wbf   = (float*)alloc(641 * 4);
  u16*   HA    = (u16*)  alloc((size_t)N * 64 * 2);
  u16*   HT    = (u16*)  alloc((size_t)N * 64 * 2);
  float* outf  = (float*)alloc((size_t)N * 4);

  int GN = (N + 255) / 256;
  int NT = (N + 63) / 64;

  k_flag<<<1, 256, 0, stream>>>(x, flag, ssum, bcnt);
  k_conv_w<<<(24576 + 641 + 255) / 256, 256, 0, stream>>>(W1, b1, W2, b2, f1w, f1b, f2w, f2b,
                                                          wbh, wbf, flag);
  // CSR build (bucketed, 256-node buckets)
  k_bcount<<<GEB, 256, 0, stream>>>(eidx, E, bcnt, bhist);
  k_bscan<<<1, 512, 0, stream>>>(bcnt, bbase, bcur);
  k_bfill<<<GEB, 256, 0, stream>>>(eidx, E, bhist, bcur, bdata);
  k_csr<<<NB, 256, 0, stream>>>(bdata, bbase, bcnt, deg, dinv, ptr, crow, N);

  // conv1 (reads raw x, converts inline)
  k_xform<<<NT, 256, 0, stream>>>(x, 0, flag, wbh + 0, dinv, HT, N);
  k_agg<<<(N + 3) / 4, 256, 0, stream>>>(HT, HA, crow, ptr, deg, dinv, wbf + 0, N);
  // conv2
  k_xform<<<NT, 256, 0, stream>>>(HA, 1, flag, wbh + 4096, dinv, HT, N);
  k_agg<<<(N + 3) / 4, 256, 0, stream>>>(HT, HA, crow, ptr, deg, dinv, wbf + 64, N);
  // fused MLP + sum of squares
  k_fc<<<NT, 256, 0, stream>>>(HA, wbh + 8192, wbf, outf, ssum, N);
  // normalize + write
  k_norm<<<GN, 256, 0, stream>>>(outf, ssum, d_out, N, flag);
}